// Round 1
// baseline (1445.066 us; speedup 1.0000x reference)
//
#include <hip/hip_runtime.h>
#include <stdint.h>

#define AS1 __attribute__((address_space(1)))
#define AS3 __attribute__((address_space(3)))

typedef __bf16 bf16x8 __attribute__((ext_vector_type(8)));
typedef float f32x4 __attribute__((ext_vector_type(4)));

static __device__ __forceinline__ float bf2f(unsigned short u) {
    union { unsigned int i; float f; } x; x.i = ((unsigned int)u) << 16; return x.f;
}
static __device__ __forceinline__ unsigned short f2bf(float f) {
    union { float f; unsigned int i; } x; x.f = f;
    unsigned int u = x.i;
    unsigned int r = (u + 0x7fffu + ((u >> 16) & 1u)) >> 16;  // RNE
    return (unsigned short)r;
}

static __device__ __forceinline__ void gll16(const void* g, void* l) {
    __builtin_amdgcn_global_load_lds((const AS1 unsigned int*)g,
                                     (AS3 unsigned int*)l, 16, 0, 0);
}

// ---------------- f32 -> bf16 elementwise (vec4) ----------------
__global__ __launch_bounds__(256) void cvt_bf16_kernel(
    const float* __restrict__ src, unsigned short* __restrict__ dst, int n4) {
    int i = blockIdx.x * 256 + threadIdx.x;
    if (i >= n4) return;
    float4 v = ((const float4*)src)[i];
    ushort4 o;
    o.x = f2bf(v.x); o.y = f2bf(v.y); o.z = f2bf(v.z); o.w = f2bf(v.w);
    ((ushort4*)dst)[i] = o;
}

// ---------------- f32 [R,C] -> bf16 [C,R] transpose ----------------
__global__ __launch_bounds__(256) void transpose_cvt_kernel(
    const float* __restrict__ src, unsigned short* __restrict__ dst, int R, int C) {
    __shared__ float tile[32][33];
    int x = threadIdx.x & 31, y = threadIdx.x >> 5;  // y: 0..7
    int c0 = blockIdx.x * 32, r0 = blockIdx.y * 32;
#pragma unroll
    for (int i = 0; i < 4; i++)
        tile[y + i * 8][x] = src[(size_t)(r0 + y + i * 8) * C + (c0 + x)];
    __syncthreads();
#pragma unroll
    for (int i = 0; i < 4; i++)
        dst[(size_t)(c0 + y + i * 8) * R + (r0 + x)] = f2bf(tile[x][y + i * 8]);
}

// ---------------- bf16 MFMA GEMM: C[M,N] = A[M,K] * Bt[N,K]^T ----------------
// m97 structure: 128x128 tile, BK=32, global_load_lds width 16, 2 barriers/iter.
template <int STORE_BF16>
__global__ __launch_bounds__(256) void gemm_bt_kernel(
    const unsigned short* __restrict__ A, const unsigned short* __restrict__ Bt,
    void* __restrict__ C, int M, int N, int K) {
    __shared__ __align__(16) unsigned short As[128 * 32];
    __shared__ __align__(16) unsigned short Bs[128 * 32];
    int tid = threadIdx.x;
    int lane = tid & 63;
    int w = tid >> 6;
    int m0 = blockIdx.y * 128;
    int n0 = blockIdx.x * 128;
    int qd = lane >> 4, rc = lane & 15;
    int wm = (w >> 1) * 64, wn = (w & 1) * 64;

    f32x4 acc[4][4];
#pragma unroll
    for (int i = 0; i < 4; i++)
#pragma unroll
        for (int j = 0; j < 4; j++)
#pragma unroll
            for (int r = 0; r < 4; r++) acc[i][j][r] = 0.f;

    // staging segment indices: s in [0,512), 16B each; lds addr = s*16 = wave-uniform + lane*16
    int s0 = w * 128 + lane;
    int s1 = s0 + 64;
    int rA0 = s0 >> 2, cs0 = (s0 & 3) * 8;
    int rA1 = s1 >> 2, cs1 = (s1 & 3) * 8;
    const unsigned short* a0 = A + (size_t)(m0 + rA0) * K + cs0;
    const unsigned short* a1 = A + (size_t)(m0 + rA1) * K + cs1;
    const unsigned short* b0 = Bt + (size_t)(n0 + rA0) * K + cs0;
    const unsigned short* b1 = Bt + (size_t)(n0 + rA1) * K + cs1;
    unsigned short* lA0 = As + s0 * 8;
    unsigned short* lA1 = As + s1 * 8;
    unsigned short* lB0 = Bs + s0 * 8;
    unsigned short* lB1 = Bs + s1 * 8;

    for (int k0 = 0; k0 < K; k0 += 32) {
        __syncthreads();
        gll16(a0 + k0, lA0);
        gll16(a1 + k0, lA1);
        gll16(b0 + k0, lB0);
        gll16(b1 + k0, lB1);
        __syncthreads();
        bf16x8 af[4], bfr[4];
#pragma unroll
        for (int i = 0; i < 4; i++)
            af[i] = *(const bf16x8*)(As + (wm + i * 16 + rc) * 32 + qd * 8);
#pragma unroll
        for (int i = 0; i < 4; i++)
            bfr[i] = *(const bf16x8*)(Bs + (wn + i * 16 + rc) * 32 + qd * 8);
#pragma unroll
        for (int i = 0; i < 4; i++)
#pragma unroll
            for (int j = 0; j < 4; j++)
                acc[i][j] = __builtin_amdgcn_mfma_f32_16x16x32_bf16(af[i], bfr[j], acc[i][j], 0, 0, 0);
    }

#pragma unroll
    for (int i = 0; i < 4; i++)
#pragma unroll
        for (int j = 0; j < 4; j++)
#pragma unroll
            for (int r = 0; r < 4; r++) {
                int row = m0 + wm + i * 16 + qd * 4 + r;
                int col = n0 + wn + j * 16 + rc;
                if (STORE_BF16)
                    ((unsigned short*)C)[(size_t)row * N + col] = f2bf(acc[i][j][r]);
                else
                    ((float*)C)[(size_t)row * N + col] = acc[i][j][r];
            }
}

// ---------------- ba GEMM + beta/g computation ----------------
// grid 128 blocks x 256 threads; wave w handles 4 token-rows, lane = output col (64 cols)
__global__ __launch_bounds__(256) void bag_kernel(
    const float* __restrict__ hs, const float* __restrict__ w_ba,
    const float* __restrict__ A_log, const float* __restrict__ dt_bias,
    float* __restrict__ gg, float* __restrict__ bb) {
    int w = threadIdx.x >> 6, lane = threadIdx.x & 63;
    int r0 = blockIdx.x * 16 + w * 4;
    const float* h0 = hs + (size_t)r0 * 2048;
    float a0 = 0.f, a1 = 0.f, a2 = 0.f, a3 = 0.f;
    for (int k = 0; k < 2048; k++) {
        float wv = w_ba[k * 64 + lane];
        a0 += h0[k] * wv;
        a1 += h0[2048 + k] * wv;
        a2 += h0[4096 + k] * wv;
        a3 += h0[6144 + k] * wv;
    }
    int h = lane >> 2, idx = lane & 3;
    int vh = h * 2 + (idx & 1);
    float accs[4] = {a0, a1, a2, a3};
#pragma unroll
    for (int j = 0; j < 4; j++) {
        int t = r0 + j;
        float acc = accs[j];
        if (idx < 2) {
            bb[t * 32 + vh] = 1.f / (1.f + expf(-acc));
        } else {
            float x = acc + dt_bias[vh];
            float sp = fmaxf(x, 0.f) + log1pf(expf(-fabsf(x)));  // stable softplus
            gg[t * 32 + vh] = -expf(A_log[vh]) * sp;
        }
    }
}

// ---------------- depthwise causal conv(4) + silu + l2norm(q,k) ----------------
// one block per token; 8192 channels through LDS
__global__ __launch_bounds__(256) void conv_kernel(
    const unsigned short* __restrict__ qkvz, const float* __restrict__ conv_w,
    float* __restrict__ qn, float* __restrict__ kn, float* __restrict__ vv) {
    __shared__ float xs[8192];
    __shared__ float rs[32];
    int t = blockIdx.x;
    int s = t & 1023;
    int tid = threadIdx.x;
    size_t rowbase = (size_t)t * 12288;
    for (int i = 0; i < 32; i++) {
        int c = i * 256 + tid;
        int d = c & 127;
        int col;
        if (c < 2048) col = (c >> 7) * 768 + d;
        else if (c < 4096) col = ((c - 2048) >> 7) * 768 + 128 + d;
        else { int vh = (c - 4096) >> 7; col = (vh >> 1) * 768 + 256 + (vh & 1) * 128 + d; }
        float4 wv = *(const float4*)(conv_w + (size_t)c * 4);
        float wts[4] = {wv.x, wv.y, wv.z, wv.w};
        float acc = 0.f;
#pragma unroll
        for (int j = 0; j < 4; j++) {
            int ss = s - 3 + j;
            if (ss >= 0)
                acc += bf2f(qkvz[rowbase + (size_t)(j - 3) * 12288 + col]) * wts[j];
        }
        xs[c] = acc / (1.f + expf(-acc));  // silu
    }
    __syncthreads();
    {
        int seg = tid >> 3, part = tid & 7;  // 32 segments (16 q heads + 16 k heads)
        const float* pp = xs + seg * 128 + part * 16;
        float s2 = 0.f;
#pragma unroll
        for (int j = 0; j < 16; j++) s2 += pp[j] * pp[j];
        s2 += __shfl_xor(s2, 1);
        s2 += __shfl_xor(s2, 2);
        s2 += __shfl_xor(s2, 4);
        if (part == 0) rs[seg] = rsqrtf(s2 + 1e-6f);
    }
    __syncthreads();
    const float QS = 0.08838834764831845f;  // 128^-0.5
    for (int i = 0; i < 32; i++) {
        int c = i * 256 + tid;
        float x = xs[c];
        if (c < 2048) qn[(size_t)t * 2048 + c] = x * rs[c >> 7] * QS;
        else if (c < 4096) kn[(size_t)t * 2048 + c - 2048] = x * rs[((c - 2048) >> 7) + 16];
        else vv[(size_t)t * 4096 + c - 4096] = x;
    }
}

// ---------------- gated delta-rule recurrence ----------------
// grid 256 = (b:2) x (vh:32) x (colchunk:4); block 256 = 32 cols x 8 k-slots x 16 k-elems
__global__ __launch_bounds__(256) void rec_kernel(
    const float* __restrict__ qn, const float* __restrict__ kn, const float* __restrict__ vv,
    const float* __restrict__ gg, const float* __restrict__ bb, float* __restrict__ oo) {
    __shared__ float sk[8][128], sq[8][128], sv[8][32], se[8], sb[8];
    int bid = blockIdx.x;
    int chunk = bid & 3, vh = (bid >> 2) & 31, b = bid >> 7;
    int hk = vh >> 1;
    int col0 = chunk * 32;
    int tid = threadIdx.x;
    int colL = tid >> 3, kslot = tid & 7;
    int k0 = kslot * 16;
    int tb = b * 1024;
    float st[16];
#pragma unroll
    for (int i = 0; i < 16; i++) st[i] = 0.f;

    for (int t0 = 0; t0 < 1024; t0 += 8) {
        __syncthreads();
#pragma unroll
        for (int r = 0; r < 8; r++) {  // 2048 floats of k,q
            int tok = tb + t0 + r;
            int c = tid;
            if (c < 128) sk[r][c] = kn[((size_t)tok * 16 + hk) * 128 + c];
            else sq[r][c - 128] = qn[((size_t)tok * 16 + hk) * 128 + (c - 128)];
        }
        {
            int w = tid >> 5, c = tid & 31;
            int tok = tb + t0 + w;
            sv[w][c] = vv[((size_t)tok * 32 + vh) * 128 + col0 + c];
        }
        if (tid < 8) se[tid] = expf(gg[(tb + t0 + tid) * 32 + vh]);
        else if (tid < 16) sb[tid - 8] = bb[(tb + t0 + tid - 8) * 32 + vh];
        __syncthreads();
#pragma unroll
        for (int w = 0; w < 8; w++) {
            float eg = se[w], bta = sb[w], vt = sv[w][colL];
            float kk[16], qq[16];
            *(float4*)&kk[0]  = *(const float4*)&sk[w][k0];
            *(float4*)&kk[4]  = *(const float4*)&sk[w][k0 + 4];
            *(float4*)&kk[8]  = *(const float4*)&sk[w][k0 + 8];
            *(float4*)&kk[12] = *(const float4*)&sk[w][k0 + 12];
            *(float4*)&qq[0]  = *(const float4*)&sq[w][k0];
            *(float4*)&qq[4]  = *(const float4*)&sq[w][k0 + 4];
            *(float4*)&qq[8]  = *(const float4*)&sq[w][k0 + 8];
            *(float4*)&qq[12] = *(const float4*)&sq[w][k0 + 12];
            float c0 = 0.f, c1 = 0.f, c2 = 0.f, c3 = 0.f;
#pragma unroll
            for (int i = 0; i < 4; i++) {
                c0 += st[i] * kk[i];
                c1 += st[4 + i] * kk[4 + i];
                c2 += st[8 + i] * kk[8 + i];
                c3 += st[12 + i] * kk[12 + i];
            }
            float pk = (c0 + c1) + (c2 + c3);
            pk += __shfl_xor(pk, 1);
            pk += __shfl_xor(pk, 2);
            pk += __shfl_xor(pk, 4);
            float delta = (vt - eg * pk) * bta;
            float d0 = 0.f, d1 = 0.f, d2 = 0.f, d3 = 0.f;
#pragma unroll
            for (int i = 0; i < 4; i++) {
                st[i]      = st[i] * eg      + kk[i] * delta;      d0 += st[i] * qq[i];
                st[4 + i]  = st[4 + i] * eg  + kk[4 + i] * delta;  d1 += st[4 + i] * qq[4 + i];
                st[8 + i]  = st[8 + i] * eg  + kk[8 + i] * delta;  d2 += st[8 + i] * qq[8 + i];
                st[12 + i] = st[12 + i] * eg + kk[12 + i] * delta; d3 += st[12 + i] * qq[12 + i];
            }
            float po = (d0 + d1) + (d2 + d3);
            po += __shfl_xor(po, 1);
            po += __shfl_xor(po, 2);
            po += __shfl_xor(po, 4);
            if (kslot == 0)
                oo[((size_t)(tb + t0 + w) * 32 + vh) * 128 + col0 + colL] = po;
        }
    }
}

// ---------------- gated RMSNorm + bf16 convert ----------------
// one wave per (token, vhead); 4 per block
__global__ __launch_bounds__(256) void norm_kernel(
    const float* __restrict__ oo, const unsigned short* __restrict__ qkvz,
    const float* __restrict__ norm_w, unsigned short* __restrict__ yb) {
    int w = threadIdx.x >> 6, lane = threadIdx.x & 63;
    int g = blockIdx.x * 4 + w;
    int t = g >> 5, vh = g & 31;
    size_t ob = (size_t)g * 128;
    size_t zb = (size_t)t * 12288 + (size_t)(vh >> 1) * 768 + 512 + (vh & 1) * 128;
    float x0 = oo[ob + lane], x1 = oo[ob + 64 + lane];
    float z0 = bf2f(qkvz[zb + lane]), z1 = bf2f(qkvz[zb + 64 + lane]);
    float xg0 = x0 * (z0 / (1.f + expf(-z0)));
    float xg1 = x1 * (z1 / (1.f + expf(-z1)));
    float s = xg0 * xg0 + xg1 * xg1;
    s += __shfl_xor(s, 1);
    s += __shfl_xor(s, 2);
    s += __shfl_xor(s, 4);
    s += __shfl_xor(s, 8);
    s += __shfl_xor(s, 16);
    s += __shfl_xor(s, 32);
    float r = rsqrtf(s * (1.f / 128.f) + 1e-6f);
    size_t y0 = (size_t)t * 4096 + (size_t)vh * 128;
    yb[y0 + lane] = f2bf(xg0 * r * norm_w[lane]);
    yb[y0 + 64 + lane] = f2bf(xg1 * r * norm_w[64 + lane]);
}

extern "C" void kernel_launch(void* const* d_in, const int* in_sizes, int n_in,
                              void* d_out, int out_size, void* d_ws, size_t ws_size,
                              hipStream_t stream) {
    const float* hs      = (const float*)d_in[0];
    const float* w_qkvz  = (const float*)d_in[1];
    const float* w_ba    = (const float*)d_in[2];
    const float* conv_w  = (const float*)d_in[3];
    const float* dt_bias = (const float*)d_in[4];
    const float* A_log   = (const float*)d_in[5];
    const float* norm_w  = (const float*)d_in[6];
    const float* w_out   = (const float*)d_in[7];
    float* out = (float*)d_out;
    (void)in_sizes; (void)n_in; (void)out_size; (void)ws_size;

    char* p = (char*)d_ws;
    auto alloc = [&](size_t b) { char* r = p; p += (b + 255) & ~(size_t)255; return r; };
    unsigned short* hsb  = (unsigned short*)alloc(2048ull * 2048 * 2);   // hs bf16
    unsigned short* wqT  = (unsigned short*)alloc(12288ull * 2048 * 2);  // w_qkvz^T bf16 [N,K]
    unsigned short* woT  = (unsigned short*)alloc(2048ull * 4096 * 2);   // w_out^T bf16 [N,K]
    unsigned short* qkvz = (unsigned short*)alloc(2048ull * 12288 * 2);  // projections bf16
    float* gg = (float*)alloc(2048ull * 32 * 4);                         // log-decay
    float* bb = (float*)alloc(2048ull * 32 * 4);                         // beta
    float* qn = (float*)alloc(2048ull * 2048 * 4);                       // q normed [t,16,128]
    float* kn = (float*)alloc(2048ull * 2048 * 4);                       // k normed [t,16,128]
    float* vv = (float*)alloc(2048ull * 4096 * 4);                       // v [t,32,128]
    float* oo = (float*)alloc(2048ull * 4096 * 4);                       // recurrence out
    unsigned short* yb = (unsigned short*)alloc(2048ull * 4096 * 2);     // normed, bf16

    cvt_bf16_kernel<<<4096, 256, 0, stream>>>(hs, hsb, 2048 * 2048 / 4);
    transpose_cvt_kernel<<<dim3(12288 / 32, 2048 / 32), 256, 0, stream>>>(w_qkvz, wqT, 2048, 12288);
    transpose_cvt_kernel<<<dim3(2048 / 32, 4096 / 32), 256, 0, stream>>>(w_out, woT, 4096, 2048);
    gemm_bt_kernel<1><<<dim3(96, 16), 256, 0, stream>>>(hsb, wqT, qkvz, 2048, 12288, 2048);
    bag_kernel<<<128, 256, 0, stream>>>(hs, w_ba, A_log, dt_bias, gg, bb);
    conv_kernel<<<2048, 256, 0, stream>>>(qkvz, conv_w, qn, kn, vv);
    rec_kernel<<<256, 256, 0, stream>>>(qn, kn, vv, gg, bb, oo);
    norm_kernel<<<16384, 256, 0, stream>>>(oo, qkvz, norm_w, yb);
    gemm_bt_kernel<0><<<dim3(16, 16), 256, 0, stream>>>(yb, woT, out, 2048, 2048, 4096);
}

// Round 2
// 1228.667 us; speedup vs baseline: 1.1761x; 1.1761x over previous
//
#include <hip/hip_runtime.h>
#include <stdint.h>

#define AS1 __attribute__((address_space(1)))
#define AS3 __attribute__((address_space(3)))

typedef __bf16 bf16x8 __attribute__((ext_vector_type(8)));
typedef float f32x4 __attribute__((ext_vector_type(4)));

static __device__ __forceinline__ float bf2f(unsigned short u) {
    union { unsigned int i; float f; } x; x.i = ((unsigned int)u) << 16; return x.f;
}
static __device__ __forceinline__ unsigned short f2bf(float f) {
    union { float f; unsigned int i; } x; x.f = f;
    unsigned int u = x.i;
    unsigned int r = (u + 0x7fffu + ((u >> 16) & 1u)) >> 16;  // RNE
    return (unsigned short)r;
}

static __device__ __forceinline__ void gll16(const void* g, void* l) {
    __builtin_amdgcn_global_load_lds((const AS1 unsigned int*)g,
                                     (AS3 unsigned int*)l, 16, 0, 0);
}

// VALU-rate 16-lane row reduction: v_add_f32 with DPP row_ror:{1,2,4,8}.
// After the 4 stages every lane in a 16-lane DPP row holds the row sum.
template <int CTRL>
static __device__ __forceinline__ float dpp_rot_add(float x) {
    union { float f; int i; } u, r;
    u.f = x;
    r.i = __builtin_amdgcn_update_dpp(0, u.i, CTRL, 0xF, 0xF, true);
    return x + r.f;
}
static __device__ __forceinline__ float row16_sum(float x) {
    x = dpp_rot_add<0x121>(x);  // row_ror:1
    x = dpp_rot_add<0x122>(x);  // row_ror:2
    x = dpp_rot_add<0x124>(x);  // row_ror:4
    x = dpp_rot_add<0x128>(x);  // row_ror:8
    return x;
}

// ---------------- f32 -> bf16 elementwise (vec4) ----------------
__global__ __launch_bounds__(256) void cvt_bf16_kernel(
    const float* __restrict__ src, unsigned short* __restrict__ dst, int n4) {
    int i = blockIdx.x * 256 + threadIdx.x;
    if (i >= n4) return;
    float4 v = ((const float4*)src)[i];
    ushort4 o;
    o.x = f2bf(v.x); o.y = f2bf(v.y); o.z = f2bf(v.z); o.w = f2bf(v.w);
    ((ushort4*)dst)[i] = o;
}

// ---------------- f32 [R,C] -> bf16 [C,R] transpose ----------------
__global__ __launch_bounds__(256) void transpose_cvt_kernel(
    const float* __restrict__ src, unsigned short* __restrict__ dst, int R, int C) {
    __shared__ float tile[32][33];
    int x = threadIdx.x & 31, y = threadIdx.x >> 5;  // y: 0..7
    int c0 = blockIdx.x * 32, r0 = blockIdx.y * 32;
#pragma unroll
    for (int i = 0; i < 4; i++)
        tile[y + i * 8][x] = src[(size_t)(r0 + y + i * 8) * C + (c0 + x)];
    __syncthreads();
#pragma unroll
    for (int i = 0; i < 4; i++)
        dst[(size_t)(c0 + y + i * 8) * R + (r0 + x)] = f2bf(tile[x][y + i * 8]);
}

// ---------------- bf16 MFMA GEMM: C[M,N] = A[M,K] * Bt[N,K]^T ----------------
// m97 structure: 128x128 tile, BK=32, global_load_lds width 16, 2 barriers/iter.
template <int STORE_BF16>
__global__ __launch_bounds__(256) void gemm_bt_kernel(
    const unsigned short* __restrict__ A, const unsigned short* __restrict__ Bt,
    void* __restrict__ C, int M, int N, int K) {
    __shared__ __align__(16) unsigned short As[128 * 32];
    __shared__ __align__(16) unsigned short Bs[128 * 32];
    int tid = threadIdx.x;
    int lane = tid & 63;
    int w = tid >> 6;
    int m0 = blockIdx.y * 128;
    int n0 = blockIdx.x * 128;
    int qd = lane >> 4, rc = lane & 15;
    int wm = (w >> 1) * 64, wn = (w & 1) * 64;

    f32x4 acc[4][4];
#pragma unroll
    for (int i = 0; i < 4; i++)
#pragma unroll
        for (int j = 0; j < 4; j++)
#pragma unroll
            for (int r = 0; r < 4; r++) acc[i][j][r] = 0.f;

    int s0 = w * 128 + lane;
    int s1 = s0 + 64;
    int rA0 = s0 >> 2, cs0 = (s0 & 3) * 8;
    int rA1 = s1 >> 2, cs1 = (s1 & 3) * 8;
    const unsigned short* a0 = A + (size_t)(m0 + rA0) * K + cs0;
    const unsigned short* a1 = A + (size_t)(m0 + rA1) * K + cs1;
    const unsigned short* b0 = Bt + (size_t)(n0 + rA0) * K + cs0;
    const unsigned short* b1 = Bt + (size_t)(n0 + rA1) * K + cs1;
    unsigned short* lA0 = As + s0 * 8;
    unsigned short* lA1 = As + s1 * 8;
    unsigned short* lB0 = Bs + s0 * 8;
    unsigned short* lB1 = Bs + s1 * 8;

    for (int k0 = 0; k0 < K; k0 += 32) {
        __syncthreads();
        gll16(a0 + k0, lA0);
        gll16(a1 + k0, lA1);
        gll16(b0 + k0, lB0);
        gll16(b1 + k0, lB1);
        __syncthreads();
        bf16x8 af[4], bfr[4];
#pragma unroll
        for (int i = 0; i < 4; i++)
            af[i] = *(const bf16x8*)(As + (wm + i * 16 + rc) * 32 + qd * 8);
#pragma unroll
        for (int i = 0; i < 4; i++)
            bfr[i] = *(const bf16x8*)(Bs + (wn + i * 16 + rc) * 32 + qd * 8);
#pragma unroll
        for (int i = 0; i < 4; i++)
#pragma unroll
            for (int j = 0; j < 4; j++)
                acc[i][j] = __builtin_amdgcn_mfma_f32_16x16x32_bf16(af[i], bfr[j], acc[i][j], 0, 0, 0);
    }

#pragma unroll
    for (int i = 0; i < 4; i++)
#pragma unroll
        for (int j = 0; j < 4; j++)
#pragma unroll
            for (int r = 0; r < 4; r++) {
                int row = m0 + wm + i * 16 + qd * 4 + r;
                int col = n0 + wn + j * 16 + rc;
                if (STORE_BF16)
                    ((unsigned short*)C)[(size_t)row * N + col] = f2bf(acc[i][j][r]);
                else
                    ((float*)C)[(size_t)row * N + col] = acc[i][j][r];
            }
}

// ---------------- ba GEMM + beta/g computation ----------------
__global__ __launch_bounds__(256) void bag_kernel(
    const float* __restrict__ hs, const float* __restrict__ w_ba,
    const float* __restrict__ A_log, const float* __restrict__ dt_bias,
    float* __restrict__ gg, float* __restrict__ bb) {
    int w = threadIdx.x >> 6, lane = threadIdx.x & 63;
    int r0 = blockIdx.x * 16 + w * 4;
    const float* h0 = hs + (size_t)r0 * 2048;
    float a0 = 0.f, a1 = 0.f, a2 = 0.f, a3 = 0.f;
    for (int k = 0; k < 2048; k++) {
        float wv = w_ba[k * 64 + lane];
        a0 += h0[k] * wv;
        a1 += h0[2048 + k] * wv;
        a2 += h0[4096 + k] * wv;
        a3 += h0[6144 + k] * wv;
    }
    int h = lane >> 2, idx = lane & 3;
    int vh = h * 2 + (idx & 1);
    float accs[4] = {a0, a1, a2, a3};
#pragma unroll
    for (int j = 0; j < 4; j++) {
        int t = r0 + j;
        float acc = accs[j];
        if (idx < 2) {
            bb[t * 32 + vh] = 1.f / (1.f + expf(-acc));
        } else {
            float x = acc + dt_bias[vh];
            float sp = fmaxf(x, 0.f) + log1pf(expf(-fabsf(x)));  // stable softplus
            gg[t * 32 + vh] = -expf(A_log[vh]) * sp;
        }
    }
}

// ---------------- depthwise causal conv(4) + silu + l2norm(q,k) ----------------
__global__ __launch_bounds__(256) void conv_kernel(
    const unsigned short* __restrict__ qkvz, const float* __restrict__ conv_w,
    float* __restrict__ qn, float* __restrict__ kn, float* __restrict__ vv) {
    __shared__ float xs[8192];
    __shared__ float rs[32];
    int t = blockIdx.x;
    int s = t & 1023;
    int tid = threadIdx.x;
    size_t rowbase = (size_t)t * 12288;
    for (int i = 0; i < 32; i++) {
        int c = i * 256 + tid;
        int d = c & 127;
        int col;
        if (c < 2048) col = (c >> 7) * 768 + d;
        else if (c < 4096) col = ((c - 2048) >> 7) * 768 + 128 + d;
        else { int vh = (c - 4096) >> 7; col = (vh >> 1) * 768 + 256 + (vh & 1) * 128 + d; }
        float4 wv = *(const float4*)(conv_w + (size_t)c * 4);
        float wts[4] = {wv.x, wv.y, wv.z, wv.w};
        float acc = 0.f;
#pragma unroll
        for (int j = 0; j < 4; j++) {
            int ss = s - 3 + j;
            if (ss >= 0)
                acc += bf2f(qkvz[rowbase + (size_t)(j - 3) * 12288 + col]) * wts[j];
        }
        xs[c] = acc / (1.f + expf(-acc));  // silu
    }
    __syncthreads();
    {
        int seg = tid >> 3, part = tid & 7;  // 32 segments (16 q heads + 16 k heads)
        const float* pp = xs + seg * 128 + part * 16;
        float s2 = 0.f;
#pragma unroll
        for (int j = 0; j < 16; j++) s2 += pp[j] * pp[j];
        s2 += __shfl_xor(s2, 1);
        s2 += __shfl_xor(s2, 2);
        s2 += __shfl_xor(s2, 4);
        if (part == 0) rs[seg] = rsqrtf(s2 + 1e-6f);
    }
    __syncthreads();
    const float QS = 0.08838834764831845f;  // 128^-0.5
    for (int i = 0; i < 32; i++) {
        int c = i * 256 + tid;
        float x = xs[c];
        if (c < 2048) qn[(size_t)t * 2048 + c] = x * rs[c >> 7] * QS;
        else if (c < 4096) kn[(size_t)t * 2048 + c - 2048] = x * rs[((c - 2048) >> 7) + 16];
        else vv[(size_t)t * 4096 + c - 4096] = x;
    }
}

// ---------------- gated delta-rule recurrence ----------------
// grid 512 = (b:2) x (vh:32) x (colchunk:8); block 256 = 16 cols x 16 kslots x 8 k-elems.
// 2 blocks/CU -> 2 waves/SIMD for latency hiding; reductions are 16-lane DPP
// row_ror rotate-adds (VALU-rate) instead of ds_swizzle shuffles.
__global__ __launch_bounds__(256) void rec_kernel(
    const float* __restrict__ qn, const float* __restrict__ kn, const float* __restrict__ vv,
    const float* __restrict__ gg, const float* __restrict__ bb, float* __restrict__ oo) {
    __shared__ float sk[8][128], sq[8][128], sv[8][16], se[8], sb[8];
    int bid = blockIdx.x;
    int chunk = bid & 7, vh = (bid >> 3) & 31, b = bid >> 8;
    int hk = vh >> 1;
    int col0 = chunk * 16;
    int tid = threadIdx.x;
    int colL = tid >> 4, kslot = tid & 15;
    int k0 = kslot * 8;
    int tb = b * 1024;
    float st[8];
#pragma unroll
    for (int i = 0; i < 8; i++) st[i] = 0.f;

    for (int t0 = 0; t0 < 1024; t0 += 8) {
        __syncthreads();
#pragma unroll
        for (int r = 0; r < 8; r++) {  // k,q: 8 tokens x 256 floats
            int tok = tb + t0 + r;
            int c = tid;
            if (c < 128) sk[r][c] = kn[((size_t)tok * 16 + hk) * 128 + c];
            else sq[r][c - 128] = qn[((size_t)tok * 16 + hk) * 128 + (c - 128)];
        }
        if (tid < 128) {
            int w = tid >> 4, c = tid & 15;
            int tok = tb + t0 + w;
            sv[w][c] = vv[((size_t)tok * 32 + vh) * 128 + col0 + c];
        }
        if (tid < 8) se[tid] = expf(gg[(tb + t0 + tid) * 32 + vh]);
        else if (tid < 16) sb[tid - 8] = bb[(tb + t0 + tid - 8) * 32 + vh];
        __syncthreads();
#pragma unroll
        for (int w = 0; w < 8; w++) {
            float eg = se[w], bta = sb[w], vt = sv[w][colL];
            float kk[8], qq[8];
            *(float4*)&kk[0] = *(const float4*)&sk[w][k0];
            *(float4*)&kk[4] = *(const float4*)&sk[w][k0 + 4];
            *(float4*)&qq[0] = *(const float4*)&sq[w][k0];
            *(float4*)&qq[4] = *(const float4*)&sq[w][k0 + 4];
            float c0 = 0.f, c1 = 0.f;
#pragma unroll
            for (int i = 0; i < 4; i++) {
                c0 += st[i] * kk[i];
                c1 += st[4 + i] * kk[4 + i];
            }
            float pk = row16_sum(c0 + c1);
            float delta = (vt - eg * pk) * bta;
            float d0 = 0.f, d1 = 0.f;
#pragma unroll
            for (int i = 0; i < 4; i++) {
                st[i]     = st[i] * eg     + kk[i] * delta;     d0 += st[i] * qq[i];
                st[4 + i] = st[4 + i] * eg + kk[4 + i] * delta; d1 += st[4 + i] * qq[4 + i];
            }
            float po = row16_sum(d0 + d1);
            if (kslot == 0)
                oo[((size_t)(tb + t0 + w) * 32 + vh) * 128 + col0 + colL] = po;
        }
    }
}

// ---------------- gated RMSNorm + bf16 convert ----------------
__global__ __launch_bounds__(256) void norm_kernel(
    const float* __restrict__ oo, const unsigned short* __restrict__ qkvz,
    const float* __restrict__ norm_w, unsigned short* __restrict__ yb) {
    int w = threadIdx.x >> 6, lane = threadIdx.x & 63;
    int g = blockIdx.x * 4 + w;
    int t = g >> 5, vh = g & 31;
    size_t ob = (size_t)g * 128;
    size_t zb = (size_t)t * 12288 + (size_t)(vh >> 1) * 768 + 512 + (vh & 1) * 128;
    float x0 = oo[ob + lane], x1 = oo[ob + 64 + lane];
    float z0 = bf2f(qkvz[zb + lane]), z1 = bf2f(qkvz[zb + 64 + lane]);
    float xg0 = x0 * (z0 / (1.f + expf(-z0)));
    float xg1 = x1 * (z1 / (1.f + expf(-z1)));
    float s = xg0 * xg0 + xg1 * xg1;
    s += __shfl_xor(s, 1);
    s += __shfl_xor(s, 2);
    s += __shfl_xor(s, 4);
    s += __shfl_xor(s, 8);
    s += __shfl_xor(s, 16);
    s += __shfl_xor(s, 32);
    float r = rsqrtf(s * (1.f / 128.f) + 1e-6f);
    size_t y0 = (size_t)t * 4096 + (size_t)vh * 128;
    yb[y0 + lane] = f2bf(xg0 * r * norm_w[lane]);
    yb[y0 + 64 + lane] = f2bf(xg1 * r * norm_w[64 + lane]);
}

extern "C" void kernel_launch(void* const* d_in, const int* in_sizes, int n_in,
                              void* d_out, int out_size, void* d_ws, size_t ws_size,
                              hipStream_t stream) {
    const float* hs      = (const float*)d_in[0];
    const float* w_qkvz  = (const float*)d_in[1];
    const float* w_ba    = (const float*)d_in[2];
    const float* conv_w  = (const float*)d_in[3];
    const float* dt_bias = (const float*)d_in[4];
    const float* A_log   = (const float*)d_in[5];
    const float* norm_w  = (const float*)d_in[6];
    const float* w_out   = (const float*)d_in[7];
    float* out = (float*)d_out;
    (void)in_sizes; (void)n_in; (void)out_size; (void)ws_size;

    char* p = (char*)d_ws;
    auto alloc = [&](size_t b) { char* r = p; p += (b + 255) & ~(size_t)255; return r; };
    unsigned short* hsb  = (unsigned short*)alloc(2048ull * 2048 * 2);   // hs bf16
    unsigned short* wqT  = (unsigned short*)alloc(12288ull * 2048 * 2);  // w_qkvz^T bf16 [N,K]
    unsigned short* woT  = (unsigned short*)alloc(2048ull * 4096 * 2);   // w_out^T bf16 [N,K]
    unsigned short* qkvz = (unsigned short*)alloc(2048ull * 12288 * 2);  // projections bf16
    float* gg = (float*)alloc(2048ull * 32 * 4);                         // log-decay
    float* bb = (float*)alloc(2048ull * 32 * 4);                         // beta
    float* qn = (float*)alloc(2048ull * 2048 * 4);                       // q normed [t,16,128]
    float* kn = (float*)alloc(2048ull * 2048 * 4);                       // k normed [t,16,128]
    float* vv = (float*)alloc(2048ull * 4096 * 4);                       // v [t,32,128]
    float* oo = (float*)alloc(2048ull * 4096 * 4);                       // recurrence out
    unsigned short* yb = (unsigned short*)alloc(2048ull * 4096 * 2);     // normed, bf16

    cvt_bf16_kernel<<<4096, 256, 0, stream>>>(hs, hsb, 2048 * 2048 / 4);
    transpose_cvt_kernel<<<dim3(12288 / 32, 2048 / 32), 256, 0, stream>>>(w_qkvz, wqT, 2048, 12288);
    transpose_cvt_kernel<<<dim3(2048 / 32, 4096 / 32), 256, 0, stream>>>(w_out, woT, 4096, 2048);
    gemm_bt_kernel<1><<<dim3(96, 16), 256, 0, stream>>>(hsb, wqT, qkvz, 2048, 12288, 2048);
    bag_kernel<<<128, 256, 0, stream>>>(hs, w_ba, A_log, dt_bias, gg, bb);
    conv_kernel<<<2048, 256, 0, stream>>>(qkvz, conv_w, qn, kn, vv);
    rec_kernel<<<512, 256, 0, stream>>>(qn, kn, vv, gg, bb, oo);
    norm_kernel<<<16384, 256, 0, stream>>>(oo, qkvz, norm_w, yb);
    gemm_bt_kernel<0><<<dim3(16, 16), 256, 0, stream>>>(yb, woT, out, 2048, 2048, 4096);
}

// Round 3
// 1002.721 us; speedup vs baseline: 1.4411x; 1.2253x over previous
//
#include <hip/hip_runtime.h>
#include <stdint.h>

#define AS1 __attribute__((address_space(1)))
#define AS3 __attribute__((address_space(3)))

typedef __bf16 bf16x8 __attribute__((ext_vector_type(8)));
typedef float f32x4 __attribute__((ext_vector_type(4)));

static __device__ __forceinline__ float bf2f(unsigned short u) {
    union { unsigned int i; float f; } x; x.i = ((unsigned int)u) << 16; return x.f;
}
static __device__ __forceinline__ unsigned short f2bf(float f) {
    union { float f; unsigned int i; } x; x.f = f;
    unsigned int u = x.i;
    unsigned int r = (u + 0x7fffu + ((u >> 16) & 1u)) >> 16;  // RNE
    return (unsigned short)r;
}

static __device__ __forceinline__ void gll16(const void* g, void* l) {
    __builtin_amdgcn_global_load_lds((const AS1 unsigned int*)g,
                                     (AS3 unsigned int*)l, 16, 0, 0);
}

// VALU-rate 16-lane row reduction: v_add_f32 with DPP row_ror:{1,2,4,8}.
template <int CTRL>
static __device__ __forceinline__ float dpp_rot_add(float x) {
    union { float f; int i; } u, r;
    u.f = x;
    r.i = __builtin_amdgcn_update_dpp(0, u.i, CTRL, 0xF, 0xF, true);
    return x + r.f;
}
static __device__ __forceinline__ float row16_sum(float x) {
    x = dpp_rot_add<0x121>(x);  // row_ror:1
    x = dpp_rot_add<0x122>(x);  // row_ror:2
    x = dpp_rot_add<0x124>(x);  // row_ror:4
    x = dpp_rot_add<0x128>(x);  // row_ror:8
    return x;
}

// ---------------- f32 -> bf16 elementwise (vec4) ----------------
__global__ __launch_bounds__(256) void cvt_bf16_kernel(
    const float* __restrict__ src, unsigned short* __restrict__ dst, int n4) {
    int i = blockIdx.x * 256 + threadIdx.x;
    if (i >= n4) return;
    float4 v = ((const float4*)src)[i];
    ushort4 o;
    o.x = f2bf(v.x); o.y = f2bf(v.y); o.z = f2bf(v.z); o.w = f2bf(v.w);
    ((ushort4*)dst)[i] = o;
}

// ---------------- f32 [R,C] -> bf16 [C,R] transpose ----------------
__global__ __launch_bounds__(256) void transpose_cvt_kernel(
    const float* __restrict__ src, unsigned short* __restrict__ dst, int R, int C) {
    __shared__ float tile[32][33];
    int x = threadIdx.x & 31, y = threadIdx.x >> 5;  // y: 0..7
    int c0 = blockIdx.x * 32, r0 = blockIdx.y * 32;
#pragma unroll
    for (int i = 0; i < 4; i++)
        tile[y + i * 8][x] = src[(size_t)(r0 + y + i * 8) * C + (c0 + x)];
    __syncthreads();
#pragma unroll
    for (int i = 0; i < 4; i++)
        dst[(size_t)(c0 + y + i * 8) * R + (r0 + x)] = f2bf(tile[x][y + i * 8]);
}

// ---------------- bf16 MFMA GEMM: C[M,N] = A[M,K] * Bt[N,K]^T ----------------
template <int STORE_BF16>
__global__ __launch_bounds__(256) void gemm_bt_kernel(
    const unsigned short* __restrict__ A, const unsigned short* __restrict__ Bt,
    void* __restrict__ C, int M, int N, int K) {
    __shared__ __align__(16) unsigned short As[128 * 32];
    __shared__ __align__(16) unsigned short Bs[128 * 32];
    int tid = threadIdx.x;
    int lane = tid & 63;
    int w = tid >> 6;
    int m0 = blockIdx.y * 128;
    int n0 = blockIdx.x * 128;
    int qd = lane >> 4, rc = lane & 15;
    int wm = (w >> 1) * 64, wn = (w & 1) * 64;

    f32x4 acc[4][4];
#pragma unroll
    for (int i = 0; i < 4; i++)
#pragma unroll
        for (int j = 0; j < 4; j++)
#pragma unroll
            for (int r = 0; r < 4; r++) acc[i][j][r] = 0.f;

    int s0 = w * 128 + lane;
    int s1 = s0 + 64;
    int rA0 = s0 >> 2, cs0 = (s0 & 3) * 8;
    int rA1 = s1 >> 2, cs1 = (s1 & 3) * 8;
    const unsigned short* a0 = A + (size_t)(m0 + rA0) * K + cs0;
    const unsigned short* a1 = A + (size_t)(m0 + rA1) * K + cs1;
    const unsigned short* b0 = Bt + (size_t)(n0 + rA0) * K + cs0;
    const unsigned short* b1 = Bt + (size_t)(n0 + rA1) * K + cs1;
    unsigned short* lA0 = As + s0 * 8;
    unsigned short* lA1 = As + s1 * 8;
    unsigned short* lB0 = Bs + s0 * 8;
    unsigned short* lB1 = Bs + s1 * 8;

    for (int k0 = 0; k0 < K; k0 += 32) {
        __syncthreads();
        gll16(a0 + k0, lA0);
        gll16(a1 + k0, lA1);
        gll16(b0 + k0, lB0);
        gll16(b1 + k0, lB1);
        __syncthreads();
        bf16x8 af[4], bfr[4];
#pragma unroll
        for (int i = 0; i < 4; i++)
            af[i] = *(const bf16x8*)(As + (wm + i * 16 + rc) * 32 + qd * 8);
#pragma unroll
        for (int i = 0; i < 4; i++)
            bfr[i] = *(const bf16x8*)(Bs + (wn + i * 16 + rc) * 32 + qd * 8);
#pragma unroll
        for (int i = 0; i < 4; i++)
#pragma unroll
            for (int j = 0; j < 4; j++)
                acc[i][j] = __builtin_amdgcn_mfma_f32_16x16x32_bf16(af[i], bfr[j], acc[i][j], 0, 0, 0);
    }

#pragma unroll
    for (int i = 0; i < 4; i++)
#pragma unroll
        for (int j = 0; j < 4; j++)
#pragma unroll
            for (int r = 0; r < 4; r++) {
                int row = m0 + wm + i * 16 + qd * 4 + r;
                int col = n0 + wn + j * 16 + rc;
                if (STORE_BF16)
                    ((unsigned short*)C)[(size_t)row * N + col] = f2bf(acc[i][j][r]);
                else
                    ((float*)C)[(size_t)row * N + col] = acc[i][j][r];
            }
}

// ---------------- ba GEMM + beta/g computation ----------------
__global__ __launch_bounds__(256) void bag_kernel(
    const float* __restrict__ hs, const float* __restrict__ w_ba,
    const float* __restrict__ A_log, const float* __restrict__ dt_bias,
    float* __restrict__ gg, float* __restrict__ bb) {
    int w = threadIdx.x >> 6, lane = threadIdx.x & 63;
    int r0 = blockIdx.x * 16 + w * 4;
    const float* h0 = hs + (size_t)r0 * 2048;
    float a0 = 0.f, a1 = 0.f, a2 = 0.f, a3 = 0.f;
    for (int k = 0; k < 2048; k++) {
        float wv = w_ba[k * 64 + lane];
        a0 += h0[k] * wv;
        a1 += h0[2048 + k] * wv;
        a2 += h0[4096 + k] * wv;
        a3 += h0[6144 + k] * wv;
    }
    int h = lane >> 2, idx = lane & 3;
    int vh = h * 2 + (idx & 1);
    float accs[4] = {a0, a1, a2, a3};
#pragma unroll
    for (int j = 0; j < 4; j++) {
        int t = r0 + j;
        float acc = accs[j];
        if (idx < 2) {
            bb[t * 32 + vh] = 1.f / (1.f + expf(-acc));
        } else {
            float x = acc + dt_bias[vh];
            float sp = fmaxf(x, 0.f) + log1pf(expf(-fabsf(x)));  // stable softplus
            gg[t * 32 + vh] = -expf(A_log[vh]) * sp;
        }
    }
}

// ---------------- depthwise causal conv(4) + silu + l2norm(q,k) ----------------
__global__ __launch_bounds__(256) void conv_kernel(
    const unsigned short* __restrict__ qkvz, const float* __restrict__ conv_w,
    float* __restrict__ qn, float* __restrict__ kn, float* __restrict__ vv) {
    __shared__ float xs[8192];
    __shared__ float rs[32];
    int t = blockIdx.x;
    int s = t & 1023;
    int tid = threadIdx.x;
    size_t rowbase = (size_t)t * 12288;
    for (int i = 0; i < 32; i++) {
        int c = i * 256 + tid;
        int d = c & 127;
        int col;
        if (c < 2048) col = (c >> 7) * 768 + d;
        else if (c < 4096) col = ((c - 2048) >> 7) * 768 + 128 + d;
        else { int vh = (c - 4096) >> 7; col = (vh >> 1) * 768 + 256 + (vh & 1) * 128 + d; }
        float4 wv = *(const float4*)(conv_w + (size_t)c * 4);
        float wts[4] = {wv.x, wv.y, wv.z, wv.w};
        float acc = 0.f;
#pragma unroll
        for (int j = 0; j < 4; j++) {
            int ss = s - 3 + j;
            if (ss >= 0)
                acc += bf2f(qkvz[rowbase + (size_t)(j - 3) * 12288 + col]) * wts[j];
        }
        xs[c] = acc / (1.f + expf(-acc));  // silu
    }
    __syncthreads();
    {
        int seg = tid >> 3, part = tid & 7;  // 32 segments (16 q heads + 16 k heads)
        const float* pp = xs + seg * 128 + part * 16;
        float s2 = 0.f;
#pragma unroll
        for (int j = 0; j < 16; j++) s2 += pp[j] * pp[j];
        s2 += __shfl_xor(s2, 1);
        s2 += __shfl_xor(s2, 2);
        s2 += __shfl_xor(s2, 4);
        if (part == 0) rs[seg] = rsqrtf(s2 + 1e-6f);
    }
    __syncthreads();
    const float QS = 0.08838834764831845f;  // 128^-0.5
    for (int i = 0; i < 32; i++) {
        int c = i * 256 + tid;
        float x = xs[c];
        if (c < 2048) qn[(size_t)t * 2048 + c] = x * rs[c >> 7] * QS;
        else if (c < 4096) kn[(size_t)t * 2048 + c - 2048] = x * rs[((c - 2048) >> 7) + 16];
        else vv[(size_t)t * 4096 + c - 4096] = x;
    }
}

// ---------------- gated delta-rule recurrence ----------------
// grid 512 = (b:2) x (vh:32) x (colchunk:8); block 256 = 16 cols x 16 kslots.
// No LDS, no barriers: per-lane depth-4 register ring streams k/q/v/g/beta
// straight from global (dup reads across col-groups are L1/L2 hits).
// __launch_bounds__(256,2): ~106 VGPRs live, 2 waves/SIMD.
__global__ __launch_bounds__(256, 2) void rec_kernel(
    const float* __restrict__ qn, const float* __restrict__ kn, const float* __restrict__ vv,
    const float* __restrict__ gg, const float* __restrict__ bb, float* __restrict__ oo) {
    int bid = blockIdx.x;
    int cc = bid & 7, vh = (bid >> 3) & 31, b = bid >> 8;
    int hk = vh >> 1;
    int tid = threadIdx.x;
    int c = cc * 16 + (tid >> 4);   // output column
    int kslot = tid & 15;           // 16-lane DPP row = reduction group
    int k0 = kslot * 8;
    int tb = b * 1024;
    const int KS = 16 * 128;  // k/q float stride per token
    const int VS = 32 * 128;  // v/o float stride per token
    const float* kp = kn + ((size_t)tb * 16 + hk) * 128 + k0;
    const float* qp = qn + ((size_t)tb * 16 + hk) * 128 + k0;
    const float* vp = vv + ((size_t)tb * 32 + vh) * 128 + c;
    const float* gp = gg + (size_t)tb * 32 + vh;
    const float* bp = bb + (size_t)tb * 32 + vh;
    float* op = oo + ((size_t)tb * 32 + vh) * 128 + c;

    // depth-4 prefetch ring (tokens t..t+3 resident, t+4..t+7 in flight)
    float4 ka[4], kb[4], qa[4], qb[4];
    float vr[4], gr[4], br[4];
#pragma unroll
    for (int d = 0; d < 4; d++) {
        ka[d] = *(const float4*)(kp + (size_t)d * KS);
        kb[d] = *(const float4*)(kp + (size_t)d * KS + 4);
        qa[d] = *(const float4*)(qp + (size_t)d * KS);
        qb[d] = *(const float4*)(qp + (size_t)d * KS + 4);
        vr[d] = vp[(size_t)d * VS];
        gr[d] = gp[(size_t)d * 32];
        br[d] = bp[(size_t)d * 32];
    }
    kp += 4 * KS; qp += 4 * KS; vp += 4 * VS; gp += 4 * 32; bp += 4 * 32;

    float st[8];
#pragma unroll
    for (int i = 0; i < 8; i++) st[i] = 0.f;

    for (int t = 0; t < 1024; t += 4) {
#pragma unroll
        for (int d = 0; d < 4; d++) {
            // consume slot d (token t+d)
            float eg = __expf(gr[d]);
            float vt = vr[d], bta = br[d];
            float4 k0v = ka[d], k1v = kb[d], q0v = qa[d], q1v = qb[d];
            // prefetch token t+4+d into slot d (reads past the end land in
            // adjacent ws buffers: valid memory, never consumed)
            ka[d] = *(const float4*)kp;
            kb[d] = *(const float4*)(kp + 4);
            qa[d] = *(const float4*)qp;
            qb[d] = *(const float4*)(qp + 4);
            vr[d] = *vp;
            gr[d] = *gp;
            br[d] = *bp;
            kp += KS; qp += KS; vp += VS; gp += 32; bp += 32;
            // decay state first, then dot with k (matches ref: kv_mem on decayed S)
            st[0] *= eg; st[1] *= eg; st[2] *= eg; st[3] *= eg;
            st[4] *= eg; st[5] *= eg; st[6] *= eg; st[7] *= eg;
            float c0 = st[0] * k0v.x + st[1] * k0v.y + st[2] * k0v.z + st[3] * k0v.w;
            float c1 = st[4] * k1v.x + st[5] * k1v.y + st[6] * k1v.z + st[7] * k1v.w;
            float pk = row16_sum(c0 + c1);
            float delta = (vt - pk) * bta;
            float d0, d1;
            st[0] += k0v.x * delta; d0  = st[0] * q0v.x;
            st[1] += k0v.y * delta; d0 += st[1] * q0v.y;
            st[2] += k0v.z * delta; d0 += st[2] * q0v.z;
            st[3] += k0v.w * delta; d0 += st[3] * q0v.w;
            st[4] += k1v.x * delta; d1  = st[4] * q1v.x;
            st[5] += k1v.y * delta; d1 += st[5] * q1v.y;
            st[6] += k1v.z * delta; d1 += st[6] * q1v.z;
            st[7] += k1v.w * delta; d1 += st[7] * q1v.w;
            float po = row16_sum(d0 + d1);
            if (kslot == 0) op[0] = po;
            op += VS;
        }
    }
}

// ---------------- gated RMSNorm + bf16 convert ----------------
__global__ __launch_bounds__(256) void norm_kernel(
    const float* __restrict__ oo, const unsigned short* __restrict__ qkvz,
    const float* __restrict__ norm_w, unsigned short* __restrict__ yb) {
    int w = threadIdx.x >> 6, lane = threadIdx.x & 63;
    int g = blockIdx.x * 4 + w;
    int t = g >> 5, vh = g & 31;
    size_t ob = (size_t)g * 128;
    size_t zb = (size_t)t * 12288 + (size_t)(vh >> 1) * 768 + 512 + (vh & 1) * 128;
    float x0 = oo[ob + lane], x1 = oo[ob + 64 + lane];
    float z0 = bf2f(qkvz[zb + lane]), z1 = bf2f(qkvz[zb + 64 + lane]);
    float xg0 = x0 * (z0 / (1.f + expf(-z0)));
    float xg1 = x1 * (z1 / (1.f + expf(-z1)));
    float s = xg0 * xg0 + xg1 * xg1;
    s += __shfl_xor(s, 1);
    s += __shfl_xor(s, 2);
    s += __shfl_xor(s, 4);
    s += __shfl_xor(s, 8);
    s += __shfl_xor(s, 16);
    s += __shfl_xor(s, 32);
    float r = rsqrtf(s * (1.f / 128.f) + 1e-6f);
    size_t y0 = (size_t)t * 4096 + (size_t)vh * 128;
    yb[y0 + lane] = f2bf(xg0 * r * norm_w[lane]);
    yb[y0 + 64 + lane] = f2bf(xg1 * r * norm_w[64 + lane]);
}

extern "C" void kernel_launch(void* const* d_in, const int* in_sizes, int n_in,
                              void* d_out, int out_size, void* d_ws, size_t ws_size,
                              hipStream_t stream) {
    const float* hs      = (const float*)d_in[0];
    const float* w_qkvz  = (const float*)d_in[1];
    const float* w_ba    = (const float*)d_in[2];
    const float* conv_w  = (const float*)d_in[3];
    const float* dt_bias = (const float*)d_in[4];
    const float* A_log   = (const float*)d_in[5];
    const float* norm_w  = (const float*)d_in[6];
    const float* w_out   = (const float*)d_in[7];
    float* out = (float*)d_out;
    (void)in_sizes; (void)n_in; (void)out_size; (void)ws_size;

    char* p = (char*)d_ws;
    auto alloc = [&](size_t b) { char* r = p; p += (b + 255) & ~(size_t)255; return r; };
    float* gg = (float*)alloc(2048ull * 32 * 4);                         // log-decay
    float* bb = (float*)alloc(2048ull * 32 * 4);                         // beta
    unsigned short* hsb  = (unsigned short*)alloc(2048ull * 2048 * 2);   // hs bf16
    unsigned short* wqT  = (unsigned short*)alloc(12288ull * 2048 * 2);  // w_qkvz^T bf16 [N,K]
    unsigned short* woT  = (unsigned short*)alloc(2048ull * 4096 * 2);   // w_out^T bf16 [N,K]
    unsigned short* qkvz = (unsigned short*)alloc(2048ull * 12288 * 2);  // projections bf16
    float* qn = (float*)alloc(2048ull * 2048 * 4);                       // q normed [t,16,128]
    float* kn = (float*)alloc(2048ull * 2048 * 4);                       // k normed [t,16,128]
    float* vv = (float*)alloc(2048ull * 4096 * 4);                       // v [t,32,128]
    float* oo = (float*)alloc(2048ull * 4096 * 4);                       // recurrence out
    unsigned short* yb = (unsigned short*)alloc(2048ull * 4096 * 2);     // normed, bf16

    cvt_bf16_kernel<<<4096, 256, 0, stream>>>(hs, hsb, 2048 * 2048 / 4);
    transpose_cvt_kernel<<<dim3(12288 / 32, 2048 / 32), 256, 0, stream>>>(w_qkvz, wqT, 2048, 12288);
    transpose_cvt_kernel<<<dim3(2048 / 32, 4096 / 32), 256, 0, stream>>>(w_out, woT, 4096, 2048);
    gemm_bt_kernel<1><<<dim3(96, 16), 256, 0, stream>>>(hsb, wqT, qkvz, 2048, 12288, 2048);
    bag_kernel<<<128, 256, 0, stream>>>(hs, w_ba, A_log, dt_bias, gg, bb);
    conv_kernel<<<2048, 256, 0, stream>>>(qkvz, conv_w, qn, kn, vv);
    rec_kernel<<<512, 256, 0, stream>>>(qn, kn, vv, gg, bb, oo);
    norm_kernel<<<16384, 256, 0, stream>>>(oo, qkvz, norm_w, yb);
    gemm_bt_kernel<0><<<dim3(16, 16), 256, 0, stream>>>(yb, woT, out, 2048, 2048, 4096);
}

// Round 4
// 847.890 us; speedup vs baseline: 1.7043x; 1.1826x over previous
//
#include <hip/hip_runtime.h>
#include <stdint.h>

#define AS1 __attribute__((address_space(1)))
#define AS3 __attribute__((address_space(3)))

typedef __bf16 bf16x8 __attribute__((ext_vector_type(8)));
typedef float f32x4 __attribute__((ext_vector_type(4)));

static __device__ __forceinline__ float bf2f(unsigned short u) {
    union { unsigned int i; float f; } x; x.i = ((unsigned int)u) << 16; return x.f;
}
static __device__ __forceinline__ unsigned short f2bf(float f) {
    union { float f; unsigned int i; } x; x.f = f;
    unsigned int u = x.i;
    unsigned int r = (u + 0x7fffu + ((u >> 16) & 1u)) >> 16;  // RNE
    return (unsigned short)r;
}

static __device__ __forceinline__ void gll16(const void* g, void* l) {
    __builtin_amdgcn_global_load_lds((const AS1 unsigned int*)g,
                                     (AS3 unsigned int*)l, 16, 0, 0);
}

// ---------------- f32 -> bf16 elementwise (vec4) ----------------
__global__ __launch_bounds__(256) void cvt_bf16_kernel(
    const float* __restrict__ src, unsigned short* __restrict__ dst, int n4) {
    int i = blockIdx.x * 256 + threadIdx.x;
    if (i >= n4) return;
    float4 v = ((const float4*)src)[i];
    ushort4 o;
    o.x = f2bf(v.x); o.y = f2bf(v.y); o.z = f2bf(v.z); o.w = f2bf(v.w);
    ((ushort4*)dst)[i] = o;
}

// ---------------- f32 [R,C] -> bf16 [C,R] transpose ----------------
__global__ __launch_bounds__(256) void transpose_cvt_kernel(
    const float* __restrict__ src, unsigned short* __restrict__ dst, int R, int C) {
    __shared__ float tile[32][33];
    int x = threadIdx.x & 31, y = threadIdx.x >> 5;
    int c0 = blockIdx.x * 32, r0 = blockIdx.y * 32;
#pragma unroll
    for (int i = 0; i < 4; i++)
        tile[y + i * 8][x] = src[(size_t)(r0 + y + i * 8) * C + (c0 + x)];
    __syncthreads();
#pragma unroll
    for (int i = 0; i < 4; i++)
        dst[(size_t)(c0 + y + i * 8) * R + (r0 + x)] = f2bf(tile[x][y + i * 8]);
}

// ---------------- bf16 MFMA GEMM: C[M,N] = A[M,K] * Bt[N,K]^T ----------------
template <int STORE_BF16>
__global__ __launch_bounds__(256) void gemm_bt_kernel(
    const unsigned short* __restrict__ A, const unsigned short* __restrict__ Bt,
    void* __restrict__ C, int M, int N, int K) {
    __shared__ __align__(16) unsigned short As[128 * 32];
    __shared__ __align__(16) unsigned short Bs[128 * 32];
    int tid = threadIdx.x;
    int lane = tid & 63;
    int w = tid >> 6;
    int m0 = blockIdx.y * 128;
    int n0 = blockIdx.x * 128;
    int qd = lane >> 4, rc = lane & 15;
    int wm = (w >> 1) * 64, wn = (w & 1) * 64;

    f32x4 acc[4][4];
#pragma unroll
    for (int i = 0; i < 4; i++)
#pragma unroll
        for (int j = 0; j < 4; j++)
#pragma unroll
            for (int r = 0; r < 4; r++) acc[i][j][r] = 0.f;

    int s0 = w * 128 + lane;
    int s1 = s0 + 64;
    int rA0 = s0 >> 2, cs0 = (s0 & 3) * 8;
    int rA1 = s1 >> 2, cs1 = (s1 & 3) * 8;
    const unsigned short* a0 = A + (size_t)(m0 + rA0) * K + cs0;
    const unsigned short* a1 = A + (size_t)(m0 + rA1) * K + cs1;
    const unsigned short* b0 = Bt + (size_t)(n0 + rA0) * K + cs0;
    const unsigned short* b1 = Bt + (size_t)(n0 + rA1) * K + cs1;
    unsigned short* lA0 = As + s0 * 8;
    unsigned short* lA1 = As + s1 * 8;
    unsigned short* lB0 = Bs + s0 * 8;
    unsigned short* lB1 = Bs + s1 * 8;

    for (int k0 = 0; k0 < K; k0 += 32) {
        __syncthreads();
        gll16(a0 + k0, lA0);
        gll16(a1 + k0, lA1);
        gll16(b0 + k0, lB0);
        gll16(b1 + k0, lB1);
        __syncthreads();
        bf16x8 af[4], bfr[4];
#pragma unroll
        for (int i = 0; i < 4; i++)
            af[i] = *(const bf16x8*)(As + (wm + i * 16 + rc) * 32 + qd * 8);
#pragma unroll
        for (int i = 0; i < 4; i++)
            bfr[i] = *(const bf16x8*)(Bs + (wn + i * 16 + rc) * 32 + qd * 8);
#pragma unroll
        for (int i = 0; i < 4; i++)
#pragma unroll
            for (int j = 0; j < 4; j++)
                acc[i][j] = __builtin_amdgcn_mfma_f32_16x16x32_bf16(af[i], bfr[j], acc[i][j], 0, 0, 0);
    }

#pragma unroll
    for (int i = 0; i < 4; i++)
#pragma unroll
        for (int j = 0; j < 4; j++)
#pragma unroll
            for (int r = 0; r < 4; r++) {
                int row = m0 + wm + i * 16 + qd * 4 + r;
                int col = n0 + wn + j * 16 + rc;
                if (STORE_BF16)
                    ((unsigned short*)C)[(size_t)row * N + col] = f2bf(acc[i][j][r]);
                else
                    ((float*)C)[(size_t)row * N + col] = acc[i][j][r];
            }
}

// ---------------- ba GEMM + beta/g computation ----------------
__global__ __launch_bounds__(256) void bag_kernel(
    const float* __restrict__ hs, const float* __restrict__ w_ba,
    const float* __restrict__ A_log, const float* __restrict__ dt_bias,
    float* __restrict__ gg, float* __restrict__ bb) {
    int w = threadIdx.x >> 6, lane = threadIdx.x & 63;
    int r0 = blockIdx.x * 16 + w * 4;
    const float* h0 = hs + (size_t)r0 * 2048;
    float a0 = 0.f, a1 = 0.f, a2 = 0.f, a3 = 0.f;
    for (int k = 0; k < 2048; k++) {
        float wv = w_ba[k * 64 + lane];
        a0 += h0[k] * wv;
        a1 += h0[2048 + k] * wv;
        a2 += h0[4096 + k] * wv;
        a3 += h0[6144 + k] * wv;
    }
    int h = lane >> 2, idx = lane & 3;
    int vh = h * 2 + (idx & 1);
    float accs[4] = {a0, a1, a2, a3};
#pragma unroll
    for (int j = 0; j < 4; j++) {
        int t = r0 + j;
        float acc = accs[j];
        if (idx < 2) {
            bb[t * 32 + vh] = 1.f / (1.f + expf(-acc));
        } else {
            float x = acc + dt_bias[vh];
            float sp = fmaxf(x, 0.f) + log1pf(expf(-fabsf(x)));
            gg[t * 32 + vh] = -expf(A_log[vh]) * sp;
        }
    }
}

// ---------------- depthwise causal conv(4) + silu + l2norm(q,k) ----------------
// now emits q,k as bf16 [t][16][128] for the MFMA-chunked recurrence; v stays fp32
__global__ __launch_bounds__(256) void conv_kernel(
    const unsigned short* __restrict__ qkvz, const float* __restrict__ conv_w,
    unsigned short* __restrict__ qb, unsigned short* __restrict__ kb,
    float* __restrict__ vv) {
    __shared__ float xs[8192];
    __shared__ float rs[32];
    int t = blockIdx.x;
    int s = t & 1023;
    int tid = threadIdx.x;
    size_t rowbase = (size_t)t * 12288;
    for (int i = 0; i < 32; i++) {
        int c = i * 256 + tid;
        int d = c & 127;
        int col;
        if (c < 2048) col = (c >> 7) * 768 + d;
        else if (c < 4096) col = ((c - 2048) >> 7) * 768 + 128 + d;
        else { int vh = (c - 4096) >> 7; col = (vh >> 1) * 768 + 256 + (vh & 1) * 128 + d; }
        float4 wv = *(const float4*)(conv_w + (size_t)c * 4);
        float wts[4] = {wv.x, wv.y, wv.z, wv.w};
        float acc = 0.f;
#pragma unroll
        for (int j = 0; j < 4; j++) {
            int ss = s - 3 + j;
            if (ss >= 0)
                acc += bf2f(qkvz[rowbase + (size_t)(j - 3) * 12288 + col]) * wts[j];
        }
        xs[c] = acc / (1.f + expf(-acc));
    }
    __syncthreads();
    {
        int seg = tid >> 3, part = tid & 7;
        const float* pp = xs + seg * 128 + part * 16;
        float s2 = 0.f;
#pragma unroll
        for (int j = 0; j < 16; j++) s2 += pp[j] * pp[j];
        s2 += __shfl_xor(s2, 1);
        s2 += __shfl_xor(s2, 2);
        s2 += __shfl_xor(s2, 4);
        if (part == 0) rs[seg] = rsqrtf(s2 + 1e-6f);
    }
    __syncthreads();
    const float QS = 0.08838834764831845f;  // 128^-0.5
    for (int i = 0; i < 32; i++) {
        int c = i * 256 + tid;
        float x = xs[c];
        if (c < 2048) qb[(size_t)t * 2048 + c] = f2bf(x * rs[c >> 7] * QS);
        else if (c < 4096) kb[(size_t)t * 2048 + c - 2048] = f2bf(x * rs[((c - 2048) >> 7) + 16]);
        else vv[(size_t)t * 4096 + c - 4096] = x;
    }
}

// ---------------- gated delta-rule recurrence: chunked (C=64) via MFMA ----------
// grid 256 = (b:2) x (vh:32) x (dv-slice:4 of 32); block 256 = 4 waves.
// Per chunk (math, with c_i = cumsum(g), all exp args <= 0 so no overflow):
//   A = K K^T ; T = I + lower(diag(beta) * exp(ci-cj) * A)
//   solve T Delta = diag(beta) (V - diag(exp(ci)) K S0)      [4x16 blocked FS]
//   O = diag(exp(ci)) Q S0 + (tril_incl(exp(ci-cj) * Q K^T)) Delta
//   S <- exp(c63) S0 + K^T (diag(exp(c63-cj)) Delta)
// MFMA frag layouts (m89/m120 verified, same as gemm_bt_kernel above):
//   A[m=lane&15][k=(lane>>4)*8+j], B[n=lane&15][k=(lane>>4)*8+j],
//   C col=lane&15, row=(lane>>4)*4+reg.
__global__ __launch_bounds__(256, 1) void rec_kernel(
    const unsigned short* __restrict__ qb, const unsigned short* __restrict__ kb,
    const float* __restrict__ vv, const float* __restrict__ gg,
    const float* __restrict__ bb, float* __restrict__ oo) {
    __shared__ __align__(16) unsigned short Tb[64 * 72];   // -beta_i*exp(ci-cj)*A, i>j else 0
    __shared__ __align__(16) unsigned short Pb[64 * 72];   // exp(ci-cj)*QK^T, i>=j else 0
    __shared__ __align__(16) unsigned short Dbt[32 * 72];  // Delta^T bf16 [dv][tok]
    __shared__ __align__(16) unsigned short Kt[128 * 72];  // K^T bf16 [dk][tok]
    __shared__ __align__(16) unsigned short St[32 * 136];  // S^T bf16 [dv][dk]
    __shared__ float Td[4 * 16 * 17];                      // +T diag blocks fp32
    __shared__ float RHS[64 * 33];                         // rhs / tmp fp32
    __shared__ __align__(16) float cc[64];
    __shared__ __align__(16) float bet[64];
    __shared__ __align__(16) float lam[64];
    __shared__ __align__(16) float ex64[64];
    __shared__ float lamT[1];

    int bid = blockIdx.x;
    int slice = bid & 3, vh = (bid >> 2) & 31, b = bid >> 7;
    int hk = vh >> 1, dvo = slice * 32, tb = b * 1024;
    int tid = threadIdx.x;
    int wv = tid >> 6, lane = tid & 63;
    int qd = lane >> 4, rc = lane & 15;
    int rowb = (wv & 1) * 32;

    // persistent state S (fp32, C-layout): wave wv owns dk rows wv*32..wv*32+31
    f32x4 sacc[2][2];
#pragma unroll
    for (int tm = 0; tm < 2; tm++)
#pragma unroll
        for (int tn = 0; tn < 2; tn++)
#pragma unroll
            for (int r = 0; r < 4; r++) sacc[tm][tn][r] = 0.f;

    for (int z = tid; z < 32 * 136 / 2; z += 256) ((unsigned int*)St)[z] = 0u;
    __syncthreads();

#pragma unroll 1
    for (int ch = 0; ch < 16; ch++) {
        int t0 = tb + ch * 64;

        // ---- P0: decay metadata (wave 0) ----
        if (tid < 64) {
            float x = gg[(size_t)(t0 + tid) * 32 + vh];
#pragma unroll
            for (int ofs = 1; ofs < 64; ofs <<= 1) {
                float up = __shfl_up(x, ofs, 64);
                if (tid >= ofs) x += up;
            }
            cc[tid] = x;
            lam[tid] = __expf(x);
            float tot = __shfl(x, 63, 64);
            ex64[tid] = __expf(tot - x);
            bet[tid] = bb[(size_t)(t0 + tid) * 32 + vh];
            if (tid == 0) lamT[0] = __expf(tot);
        }
        // ---- P1: K^T into LDS ----
#pragma unroll
        for (int rr = 0; rr < 4; rr++) {
            int idx = rr * 256 + tid;
            int tok = idx & 63, dkg = idx >> 6;  // 0..15
            const unsigned short* kr = kb + ((size_t)(t0 + tok) * 16 + hk) * 128 + dkg * 8;
            uint4 kv = *(const uint4*)kr;
            int base = (dkg * 8) * 72 + tok;
            Kt[base]       = (unsigned short)(kv.x & 0xffff);
            Kt[base + 72]  = (unsigned short)(kv.x >> 16);
            Kt[base + 144] = (unsigned short)(kv.y & 0xffff);
            Kt[base + 216] = (unsigned short)(kv.y >> 16);
            Kt[base + 288] = (unsigned short)(kv.z & 0xffff);
            Kt[base + 360] = (unsigned short)(kv.z >> 16);
            Kt[base + 432] = (unsigned short)(kv.w & 0xffff);
            Kt[base + 504] = (unsigned short)(kv.w >> 16);
        }
        __syncthreads();

        // ---- P2: [K;Q] K^T (A and P), frags direct from global ----
        {
            const unsigned short* src = (wv >= 2) ? qb : kb;
            f32x4 acc[2][4];
#pragma unroll
            for (int tm = 0; tm < 2; tm++)
#pragma unroll
                for (int tn = 0; tn < 4; tn++)
#pragma unroll
                    for (int r = 0; r < 4; r++) acc[tm][tn][r] = 0.f;
#pragma unroll
            for (int ks = 0; ks < 4; ks++) {
                bf16x8 af[2], bfr[4];
#pragma unroll
                for (int tm = 0; tm < 2; tm++) {
                    int row = rowb + tm * 16 + rc;
                    af[tm] = *(const bf16x8*)(src + ((size_t)(t0 + row) * 16 + hk) * 128 + ks * 32 + qd * 8);
                }
#pragma unroll
                for (int tn = 0; tn < 4; tn++) {
                    int row = tn * 16 + rc;
                    bfr[tn] = *(const bf16x8*)(kb + ((size_t)(t0 + row) * 16 + hk) * 128 + ks * 32 + qd * 8);
                }
#pragma unroll
                for (int tm = 0; tm < 2; tm++)
#pragma unroll
                    for (int tn = 0; tn < 4; tn++)
                        acc[tm][tn] = __builtin_amdgcn_mfma_f32_16x16x32_bf16(af[tm], bfr[tn], acc[tm][tn], 0, 0, 0);
            }
            if (wv < 2) {
#pragma unroll
                for (int tm = 0; tm < 2; tm++)
#pragma unroll
                    for (int tn = 0; tn < 4; tn++)
#pragma unroll
                        for (int r = 0; r < 4; r++) {
                            int i = rowb + tm * 16 + qd * 4 + r;
                            int j = tn * 16 + rc;
                            float val = acc[tm][tn][r];
                            float tv = 0.f;
                            if (i > j) tv = bet[i] * __expf(cc[i] - cc[j]) * val;
                            Tb[i * 72 + j] = f2bf(-tv);
                            if ((i >> 4) == (j >> 4) && i > j)
                                Td[(i >> 4) * 272 + (i & 15) * 17 + (j & 15)] = tv;
                        }
            } else {
#pragma unroll
                for (int tm = 0; tm < 2; tm++)
#pragma unroll
                    for (int tn = 0; tn < 4; tn++)
#pragma unroll
                        for (int r = 0; r < 4; r++) {
                            int i = rowb + tm * 16 + qd * 4 + r;
                            int j = tn * 16 + rc;
                            float ev = (i >= j) ? __expf(cc[i] - cc[j]) : 0.f;
                            Pb[i * 72 + j] = f2bf(ev * acc[tm][tn][r]);
                        }
            }
        }
        __syncthreads();

        // ---- P3: [K;Q] S0 ; RHS for waves 0/1, O-base for waves 2/3 ----
        f32x4 oacc[2][2];
        {
            const unsigned short* src = (wv >= 2) ? qb : kb;
            f32x4 acc[2][2];
#pragma unroll
            for (int tm = 0; tm < 2; tm++)
#pragma unroll
                for (int tn = 0; tn < 2; tn++)
#pragma unroll
                    for (int r = 0; r < 4; r++) acc[tm][tn][r] = 0.f;
#pragma unroll
            for (int ks = 0; ks < 4; ks++) {
                bf16x8 af[2], bfr[2];
#pragma unroll
                for (int tm = 0; tm < 2; tm++) {
                    int row = rowb + tm * 16 + rc;
                    af[tm] = *(const bf16x8*)(src + ((size_t)(t0 + row) * 16 + hk) * 128 + ks * 32 + qd * 8);
                }
#pragma unroll
                for (int tn = 0; tn < 2; tn++)
                    bfr[tn] = *(const bf16x8*)&St[(tn * 16 + rc) * 136 + ks * 32 + qd * 8];
#pragma unroll
                for (int tm = 0; tm < 2; tm++)
#pragma unroll
                    for (int tn = 0; tn < 2; tn++)
                        acc[tm][tn] = __builtin_amdgcn_mfma_f32_16x16x32_bf16(af[tm], bfr[tn], acc[tm][tn], 0, 0, 0);
            }
            if (wv < 2) {
#pragma unroll
                for (int tm = 0; tm < 2; tm++)
#pragma unroll
                    for (int tn = 0; tn < 2; tn++)
#pragma unroll
                        for (int r = 0; r < 4; r++) {
                            int i = rowb + tm * 16 + qd * 4 + r;
                            int c = tn * 16 + rc;
                            float v = vv[((size_t)(t0 + i) * 32 + vh) * 128 + dvo + c];
                            RHS[i * 33 + c] = bet[i] * (v - lam[i] * acc[tm][tn][r]);
                        }
            } else {
#pragma unroll
                for (int tm = 0; tm < 2; tm++)
#pragma unroll
                    for (int tn = 0; tn < 2; tn++)
#pragma unroll
                        for (int r = 0; r < 4; r++) {
                            int i = rowb + tm * 16 + qd * 4 + r;
                            oacc[tm][tn][r] = lam[i] * acc[tm][tn][r];
                        }
            }
        }
        for (int z = tid; z < 32 * 72 / 2; z += 256) ((unsigned int*)Dbt)[z] = 0u;
        __syncthreads();

        // ---- P4: blocked forward substitution (stage B -> wave B) ----
#pragma unroll
        for (int B = 0; B < 4; B++) {
            if (wv == B) {
                f32x4 tacc[2];
#pragma unroll
                for (int tn = 0; tn < 2; tn++)
#pragma unroll
                    for (int r = 0; r < 4; r++)
                        tacc[tn][r] = RHS[(B * 16 + qd * 4 + r) * 33 + tn * 16 + rc];
                const int nks = (B + 1) >> 1;  // 0,1,1,2
#pragma unroll
                for (int ks = 0; ks < 2; ks++) {
                    if (ks >= nks) break;
                    bf16x8 af = *(const bf16x8*)&Tb[(B * 16 + rc) * 72 + ks * 32 + qd * 8];
#pragma unroll
                    for (int tn = 0; tn < 2; tn++) {
                        bf16x8 bf_ = *(const bf16x8*)&Dbt[(tn * 16 + rc) * 72 + ks * 32 + qd * 8];
                        tacc[tn] = __builtin_amdgcn_mfma_f32_16x16x32_bf16(af, bf_, tacc[tn], 0, 0, 0);
                    }
                }
#pragma unroll
                for (int tn = 0; tn < 2; tn++)
#pragma unroll
                    for (int r = 0; r < 4; r++)
                        RHS[(B * 16 + qd * 4 + r) * 33 + tn * 16 + rc] = tacc[tn][r];
                __builtin_amdgcn_s_waitcnt(0xc07f);  // lgkmcnt(0); wave-lockstep cross-lane LDS
                if (lane < 32) {
                    float d[16];
#pragma unroll
                    for (int i2 = 0; i2 < 16; i2++) d[i2] = RHS[(B * 16 + i2) * 33 + lane];
#pragma unroll
                    for (int i2 = 1; i2 < 16; i2++)
#pragma unroll
                        for (int j2 = 0; j2 < i2; j2++)
                            d[i2] -= Td[B * 272 + i2 * 17 + j2] * d[j2];
#pragma unroll
                    for (int i2 = 0; i2 < 16; i2++)
                        Dbt[lane * 72 + B * 16 + i2] = f2bf(d[i2]);
                }
            }
            __syncthreads();
        }

        // ---- P5: O += (E.P) Delta (waves 2,3) ; P6: S update (all waves) ----
        float l64 = lamT[0];
        if (wv >= 2) {
#pragma unroll
            for (int ks = 0; ks < 2; ks++) {
                bf16x8 af[2], bfr[2];
#pragma unroll
                for (int tm = 0; tm < 2; tm++)
                    af[tm] = *(const bf16x8*)&Pb[(rowb + tm * 16 + rc) * 72 + ks * 32 + qd * 8];
#pragma unroll
                for (int tn = 0; tn < 2; tn++)
                    bfr[tn] = *(const bf16x8*)&Dbt[(tn * 16 + rc) * 72 + ks * 32 + qd * 8];
#pragma unroll
                for (int tm = 0; tm < 2; tm++)
#pragma unroll
                    for (int tn = 0; tn < 2; tn++)
                        oacc[tm][tn] = __builtin_amdgcn_mfma_f32_16x16x32_bf16(af[tm], bfr[tn], oacc[tm][tn], 0, 0, 0);
            }
#pragma unroll
            for (int tm = 0; tm < 2; tm++)
#pragma unroll
                for (int tn = 0; tn < 2; tn++)
#pragma unroll
                    for (int r = 0; r < 4; r++) {
                        int i = rowb + tm * 16 + qd * 4 + r;
                        int c = tn * 16 + rc;
                        oo[((size_t)(t0 + i) * 32 + vh) * 128 + dvo + c] = oacc[tm][tn][r];
                    }
        }
        {
#pragma unroll
            for (int tm = 0; tm < 2; tm++)
#pragma unroll
                for (int tn = 0; tn < 2; tn++)
#pragma unroll
                    for (int r = 0; r < 4; r++) sacc[tm][tn][r] *= l64;
#pragma unroll
            for (int ks = 0; ks < 2; ks++) {
                float4 e0 = *(const float4*)&ex64[ks * 32 + qd * 8];
                float4 e1 = *(const float4*)&ex64[ks * 32 + qd * 8 + 4];
                bf16x8 bfr[2];
#pragma unroll
                for (int tn = 0; tn < 2; tn++) {
                    bf16x8 braw = *(const bf16x8*)&Dbt[(tn * 16 + rc) * 72 + ks * 32 + qd * 8];
                    bf16x8 bs;
                    bs[0] = (__bf16)((float)braw[0] * e0.x);
                    bs[1] = (__bf16)((float)braw[1] * e0.y);
                    bs[2] = (__bf16)((float)braw[2] * e0.z);
                    bs[3] = (__bf16)((float)braw[3] * e0.w);
                    bs[4] = (__bf16)((float)braw[4] * e1.x);
                    bs[5] = (__bf16)((float)braw[5] * e1.y);
                    bs[6] = (__bf16)((float)braw[6] * e1.z);
                    bs[7] = (__bf16)((float)braw[7] * e1.w);
                    bfr[tn] = bs;
                }
                bf16x8 af[2];
#pragma unroll
                for (int tm = 0; tm < 2; tm++)
                    af[tm] = *(const bf16x8*)&Kt[(wv * 32 + tm * 16 + rc) * 72 + ks * 32 + qd * 8];
#pragma unroll
                for (int tm = 0; tm < 2; tm++)
#pragma unroll
                    for (int tn = 0; tn < 2; tn++)
                        sacc[tm][tn] = __builtin_amdgcn_mfma_f32_16x16x32_bf16(af[tm], bfr[tn], sacc[tm][tn], 0, 0, 0);
            }
#pragma unroll
            for (int tm = 0; tm < 2; tm++)
#pragma unroll
                for (int tn = 0; tn < 2; tn++)
#pragma unroll
                    for (int r = 0; r < 4; r++) {
                        int dk = wv * 32 + tm * 16 + qd * 4 + r;
                        int c = tn * 16 + rc;
                        St[c * 136 + dk] = f2bf(sacc[tm][tn][r]);
                    }
        }
        __syncthreads();
    }
}

// ---------------- gated RMSNorm + bf16 convert ----------------
__global__ __launch_bounds__(256) void norm_kernel(
    const float* __restrict__ oo, const unsigned short* __restrict__ qkvz,
    const float* __restrict__ norm_w, unsigned short* __restrict__ yb) {
    int w = threadIdx.x >> 6, lane = threadIdx.x & 63;
    int g = blockIdx.x * 4 + w;
    int t = g >> 5, vh = g & 31;
    size_t ob = (size_t)g * 128;
    size_t zb = (size_t)t * 12288 + (size_t)(vh >> 1) * 768 + 512 + (vh & 1) * 128;
    float x0 = oo[ob + lane], x1 = oo[ob + 64 + lane];
    float z0 = bf2f(qkvz[zb + lane]), z1 = bf2f(qkvz[zb + 64 + lane]);
    float xg0 = x0 * (z0 / (1.f + expf(-z0)));
    float xg1 = x1 * (z1 / (1.f + expf(-z1)));
    float s = xg0 * xg0 + xg1 * xg1;
    s += __shfl_xor(s, 1);
    s += __shfl_xor(s, 2);
    s += __shfl_xor(s, 4);
    s += __shfl_xor(s, 8);
    s += __shfl_xor(s, 16);
    s += __shfl_xor(s, 32);
    float r = rsqrtf(s * (1.f / 128.f) + 1e-6f);
    size_t y0 = (size_t)t * 4096 + (size_t)vh * 128;
    yb[y0 + lane] = f2bf(xg0 * r * norm_w[lane]);
    yb[y0 + 64 + lane] = f2bf(xg1 * r * norm_w[64 + lane]);
}

extern "C" void kernel_launch(void* const* d_in, const int* in_sizes, int n_in,
                              void* d_out, int out_size, void* d_ws, size_t ws_size,
                              hipStream_t stream) {
    const float* hs      = (const float*)d_in[0];
    const float* w_qkvz  = (const float*)d_in[1];
    const float* w_ba    = (const float*)d_in[2];
    const float* conv_w  = (const float*)d_in[3];
    const float* dt_bias = (const float*)d_in[4];
    const float* A_log   = (const float*)d_in[5];
    const float* norm_w  = (const float*)d_in[6];
    const float* w_out   = (const float*)d_in[7];
    float* out = (float*)d_out;
    (void)in_sizes; (void)n_in; (void)out_size; (void)ws_size;

    char* p = (char*)d_ws;
    auto alloc = [&](size_t b) { char* r = p; p += (b + 255) & ~(size_t)255; return r; };
    float* gg = (float*)alloc(2048ull * 32 * 4);                         // log-decay
    float* bb = (float*)alloc(2048ull * 32 * 4);                         // beta
    unsigned short* hsb  = (unsigned short*)alloc(2048ull * 2048 * 2);   // hs bf16
    unsigned short* wqT  = (unsigned short*)alloc(12288ull * 2048 * 2);  // w_qkvz^T bf16 [N,K]
    unsigned short* woT  = (unsigned short*)alloc(2048ull * 4096 * 2);   // w_out^T bf16 [N,K]
    unsigned short* qkvz = (unsigned short*)alloc(2048ull * 12288 * 2);  // projections bf16
    unsigned short* qb16 = (unsigned short*)alloc(2048ull * 2048 * 2);   // q normed bf16 [t,16,128]
    unsigned short* kb16 = (unsigned short*)alloc(2048ull * 2048 * 2);   // k normed bf16 [t,16,128]
    float* vv = (float*)alloc(2048ull * 4096 * 4);                       // v [t,32,128]
    float* oo = (float*)alloc(2048ull * 4096 * 4);                       // recurrence out
    unsigned short* yb = (unsigned short*)alloc(2048ull * 4096 * 2);     // normed, bf16

    cvt_bf16_kernel<<<4096, 256, 0, stream>>>(hs, hsb, 2048 * 2048 / 4);
    transpose_cvt_kernel<<<dim3(12288 / 32, 2048 / 32), 256, 0, stream>>>(w_qkvz, wqT, 2048, 12288);
    transpose_cvt_kernel<<<dim3(2048 / 32, 4096 / 32), 256, 0, stream>>>(w_out, woT, 4096, 2048);
    gemm_bt_kernel<1><<<dim3(96, 16), 256, 0, stream>>>(hsb, wqT, qkvz, 2048, 12288, 2048);
    bag_kernel<<<128, 256, 0, stream>>>(hs, w_ba, A_log, dt_bias, gg, bb);
    conv_kernel<<<2048, 256, 0, stream>>>(qkvz, conv_w, qb16, kb16, vv);
    rec_kernel<<<256, 256, 0, stream>>>(qb16, kb16, vv, gg, bb, oo);
    norm_kernel<<<16384, 256, 0, stream>>>(oo, qkvz, norm_w, yb);
    gemm_bt_kernel<0><<<dim3(16, 16), 256, 0, stream>>>(yb, woT, out, 2048, 2048, 4096);
}

// Round 5
// 847.645 us; speedup vs baseline: 1.7048x; 1.0003x over previous
//
#include <hip/hip_runtime.h>
#include <stdint.h>

#define AS1 __attribute__((address_space(1)))
#define AS3 __attribute__((address_space(3)))

typedef __bf16 bf16x8 __attribute__((ext_vector_type(8)));
typedef float f32x4 __attribute__((ext_vector_type(4)));

static __device__ __forceinline__ float bf2f(unsigned short u) {
    union { unsigned int i; float f; } x; x.i = ((unsigned int)u) << 16; return x.f;
}
static __device__ __forceinline__ unsigned short f2bf(float f) {
    union { float f; unsigned int i; } x; x.f = f;
    unsigned int u = x.i;
    unsigned int r = (u + 0x7fffu + ((u >> 16) & 1u)) >> 16;  // RNE
    return (unsigned short)r;
}

static __device__ __forceinline__ void gll16(const void* g, void* l) {
    __builtin_amdgcn_global_load_lds((const AS1 unsigned int*)g,
                                     (AS3 unsigned int*)l, 16, 0, 0);
}

// ---------------- f32 -> bf16 elementwise (vec4) ----------------
__global__ __launch_bounds__(256) void cvt_bf16_kernel(
    const float* __restrict__ src, unsigned short* __restrict__ dst, int n4) {
    int i = blockIdx.x * 256 + threadIdx.x;
    if (i >= n4) return;
    float4 v = ((const float4*)src)[i];
    ushort4 o;
    o.x = f2bf(v.x); o.y = f2bf(v.y); o.z = f2bf(v.z); o.w = f2bf(v.w);
    ((ushort4*)dst)[i] = o;
}

// ---------------- f32 [R,C] -> bf16 [C,R] transpose ----------------
__global__ __launch_bounds__(256) void transpose_cvt_kernel(
    const float* __restrict__ src, unsigned short* __restrict__ dst, int R, int C) {
    __shared__ float tile[32][33];
    int x = threadIdx.x & 31, y = threadIdx.x >> 5;
    int c0 = blockIdx.x * 32, r0 = blockIdx.y * 32;
#pragma unroll
    for (int i = 0; i < 4; i++)
        tile[y + i * 8][x] = src[(size_t)(r0 + y + i * 8) * C + (c0 + x)];
    __syncthreads();
#pragma unroll
    for (int i = 0; i < 4; i++)
        dst[(size_t)(c0 + y + i * 8) * R + (r0 + x)] = f2bf(tile[x][y + i * 8]);
}

// ---------------- bf16 MFMA GEMM: C[M,N] = A[M,K] * Bt[N,K]^T ----------------
template <int STORE_BF16>
__global__ __launch_bounds__(256) void gemm_bt_kernel(
    const unsigned short* __restrict__ A, const unsigned short* __restrict__ Bt,
    void* __restrict__ C, int M, int N, int K) {
    __shared__ __align__(16) unsigned short As[128 * 32];
    __shared__ __align__(16) unsigned short Bs[128 * 32];
    int tid = threadIdx.x;
    int lane = tid & 63;
    int w = tid >> 6;
    int m0 = blockIdx.y * 128;
    int n0 = blockIdx.x * 128;
    int qd = lane >> 4, rc = lane & 15;
    int wm = (w >> 1) * 64, wn = (w & 1) * 64;

    f32x4 acc[4][4];
#pragma unroll
    for (int i = 0; i < 4; i++)
#pragma unroll
        for (int j = 0; j < 4; j++)
#pragma unroll
            for (int r = 0; r < 4; r++) acc[i][j][r] = 0.f;

    int s0 = w * 128 + lane;
    int s1 = s0 + 64;
    int rA0 = s0 >> 2, cs0 = (s0 & 3) * 8;
    int rA1 = s1 >> 2, cs1 = (s1 & 3) * 8;
    const unsigned short* a0 = A + (size_t)(m0 + rA0) * K + cs0;
    const unsigned short* a1 = A + (size_t)(m0 + rA1) * K + cs1;
    const unsigned short* b0 = Bt + (size_t)(n0 + rA0) * K + cs0;
    const unsigned short* b1 = Bt + (size_t)(n0 + rA1) * K + cs1;
    unsigned short* lA0 = As + s0 * 8;
    unsigned short* lA1 = As + s1 * 8;
    unsigned short* lB0 = Bs + s0 * 8;
    unsigned short* lB1 = Bs + s1 * 8;

    for (int k0 = 0; k0 < K; k0 += 32) {
        __syncthreads();
        gll16(a0 + k0, lA0);
        gll16(a1 + k0, lA1);
        gll16(b0 + k0, lB0);
        gll16(b1 + k0, lB1);
        __syncthreads();
        bf16x8 af[4], bfr[4];
#pragma unroll
        for (int i = 0; i < 4; i++)
            af[i] = *(const bf16x8*)(As + (wm + i * 16 + rc) * 32 + qd * 8);
#pragma unroll
        for (int i = 0; i < 4; i++)
            bfr[i] = *(const bf16x8*)(Bs + (wn + i * 16 + rc) * 32 + qd * 8);
#pragma unroll
        for (int i = 0; i < 4; i++)
#pragma unroll
            for (int j = 0; j < 4; j++)
                acc[i][j] = __builtin_amdgcn_mfma_f32_16x16x32_bf16(af[i], bfr[j], acc[i][j], 0, 0, 0);
    }

#pragma unroll
    for (int i = 0; i < 4; i++)
#pragma unroll
        for (int j = 0; j < 4; j++)
#pragma unroll
            for (int r = 0; r < 4; r++) {
                int row = m0 + wm + i * 16 + qd * 4 + r;
                int col = n0 + wn + j * 16 + rc;
                if (STORE_BF16)
                    ((unsigned short*)C)[(size_t)row * N + col] = f2bf(acc[i][j][r]);
                else
                    ((float*)C)[(size_t)row * N + col] = acc[i][j][r];
            }
}

// ---------------- ba GEMM + beta/g computation ----------------
// 256 blocks x 8 rows (2 rows/wave) for full-GPU coverage
__global__ __launch_bounds__(256) void bag_kernel(
    const float* __restrict__ hs, const float* __restrict__ w_ba,
    const float* __restrict__ A_log, const float* __restrict__ dt_bias,
    float* __restrict__ gg, float* __restrict__ bb) {
    int w = threadIdx.x >> 6, lane = threadIdx.x & 63;
    int r0 = blockIdx.x * 8 + w * 2;
    const float* h0 = hs + (size_t)r0 * 2048;
    float a0 = 0.f, a1 = 0.f;
    for (int k = 0; k < 2048; k++) {
        float wv = w_ba[k * 64 + lane];
        a0 += h0[k] * wv;
        a1 += h0[2048 + k] * wv;
    }
    int h = lane >> 2, idx = lane & 3;
    int vh = h * 2 + (idx & 1);
    float accs[2] = {a0, a1};
#pragma unroll
    for (int j = 0; j < 2; j++) {
        int t = r0 + j;
        float acc = accs[j];
        if (idx < 2) {
            bb[t * 32 + vh] = 1.f / (1.f + expf(-acc));
        } else {
            float x = acc + dt_bias[vh];
            float sp = fmaxf(x, 0.f) + log1pf(expf(-fabsf(x)));
            gg[t * 32 + vh] = -expf(A_log[vh]) * sp;
        }
    }
}

// ---------------- depthwise causal conv(4) + silu + l2norm(q,k) ----------------
// vectorized: 8 channels/thread, uint4 (8 x bf16) loads per tap
__global__ __launch_bounds__(256) void conv_kernel(
    const unsigned short* __restrict__ qkvz, const float* __restrict__ conv_w,
    unsigned short* __restrict__ qb, unsigned short* __restrict__ kb,
    float* __restrict__ vv) {
    __shared__ float xs[8192];
    __shared__ float rs[32];
    int t = blockIdx.x;
    int s = t & 1023;
    int tid = threadIdx.x;
    size_t rowbase = (size_t)t * 12288;
#pragma unroll
    for (int i = 0; i < 4; i++) {
        int c = (i * 256 + tid) * 8;  // 8 consecutive channels, same 128-seg
        int d = c & 127;
        int col;
        if (c < 2048) col = (c >> 7) * 768 + d;
        else if (c < 4096) col = ((c - 2048) >> 7) * 768 + 128 + d;
        else { int vh2 = (c - 4096) >> 7; col = (vh2 >> 1) * 768 + 256 + (vh2 & 1) * 128 + d; }
        float wts[8][4];
#pragma unroll
        for (int e = 0; e < 8; e++) {
            float4 t4 = *(const float4*)(conv_w + (size_t)(c + e) * 4);
            wts[e][0] = t4.x; wts[e][1] = t4.y; wts[e][2] = t4.z; wts[e][3] = t4.w;
        }
        float acc[8] = {0.f, 0.f, 0.f, 0.f, 0.f, 0.f, 0.f, 0.f};
#pragma unroll
        for (int j = 0; j < 4; j++) {
            int ss = s - 3 + j;
            if (ss >= 0) {
                uint4 u = *(const uint4*)(qkvz + rowbase + (size_t)(j - 3) * 12288 + col);
                const unsigned short* us = (const unsigned short*)&u;
#pragma unroll
                for (int e = 0; e < 8; e++) acc[e] += bf2f(us[e]) * wts[e][j];
            }
        }
#pragma unroll
        for (int e = 0; e < 8; e++) xs[c + e] = acc[e] / (1.f + expf(-acc[e]));
    }
    __syncthreads();
    {
        int seg = tid >> 3, part = tid & 7;
        const float* pp = xs + seg * 128 + part * 16;
        float s2 = 0.f;
#pragma unroll
        for (int j = 0; j < 16; j++) s2 += pp[j] * pp[j];
        s2 += __shfl_xor(s2, 1);
        s2 += __shfl_xor(s2, 2);
        s2 += __shfl_xor(s2, 4);
        if (part == 0) rs[seg] = rsqrtf(s2 + 1e-6f);
    }
    __syncthreads();
    const float QS = 0.08838834764831845f;  // 128^-0.5
#pragma unroll
    for (int i = 0; i < 4; i++) {
        int c = (i * 256 + tid) * 8;
        float x[8];
#pragma unroll
        for (int e = 0; e < 8; e++) x[e] = xs[c + e];
        if (c < 4096) {
            float sc = (c < 2048) ? rs[c >> 7] * QS : rs[((c - 2048) >> 7) + 16];
            uint4 o;
            o.x = (unsigned)f2bf(x[0] * sc) | ((unsigned)f2bf(x[1] * sc) << 16);
            o.y = (unsigned)f2bf(x[2] * sc) | ((unsigned)f2bf(x[3] * sc) << 16);
            o.z = (unsigned)f2bf(x[4] * sc) | ((unsigned)f2bf(x[5] * sc) << 16);
            o.w = (unsigned)f2bf(x[6] * sc) | ((unsigned)f2bf(x[7] * sc) << 16);
            if (c < 2048) *(uint4*)(qb + (size_t)t * 2048 + c) = o;
            else *(uint4*)(kb + (size_t)t * 2048 + c - 2048) = o;
        } else {
            float* vp = vv + (size_t)t * 4096 + c - 4096;
            *(float4*)vp = make_float4(x[0], x[1], x[2], x[3]);
            *(float4*)(vp + 4) = make_float4(x[4], x[5], x[6], x[7]);
        }
    }
}

// ---------------- gated delta-rule recurrence: chunked (C=64) via MFMA ----------
// grid 512 = (dv-slice:8 of 16) x (b:2) x (vh:32), slice-major so same-head
// blocks share an XCD; block 256 = 4 waves; 2 blocks/CU (~53 KB LDS each).
// Math identical to round-4 version (see comments there).
__global__ __launch_bounds__(256, 2) void rec_kernel(
    const unsigned short* __restrict__ qb, const unsigned short* __restrict__ kb,
    const float* __restrict__ vv, const float* __restrict__ gg,
    const float* __restrict__ bb, float* __restrict__ oo) {
    __shared__ __align__(16) unsigned short Tb[64 * 72];   // -beta_i*exp(ci-cj)*A, i>j else 0
    __shared__ __align__(16) unsigned short Pb[64 * 72];   // exp(ci-cj)*QK^T, i>=j else 0
    __shared__ __align__(16) unsigned short Dbt[16 * 72];  // Delta^T bf16 [dv][tok]
    __shared__ __align__(16) unsigned short Kt[128 * 72];  // K^T bf16 [dk][tok]
    __shared__ __align__(16) unsigned short St[16 * 136];  // S^T bf16 [dv][dk]
    __shared__ float Td[4 * 16 * 17];                      // +T diag blocks fp32
    __shared__ float RHS[64 * 17];                         // rhs / tmp fp32
    __shared__ __align__(16) float cc[64];
    __shared__ __align__(16) float bet[64];
    __shared__ __align__(16) float lam[64];
    __shared__ __align__(16) float ex64[64];
    __shared__ float lamT[1];

    int bid = blockIdx.x;
    int slice = bid >> 6;            // 0..7  (slice-major: same head -> same XCD)
    int rest = bid & 63;
    int vh = rest & 31, b = rest >> 5;
    int hk = vh >> 1, dvo = slice * 16, tb = b * 1024;
    int tid = threadIdx.x;
    int wv = tid >> 6, lane = tid & 63;
    int qd = lane >> 4, rc = lane & 15;
    int rowb = (wv & 1) * 32;

    // persistent state S (fp32, C-layout): wave wv owns dk rows wv*32..wv*32+31
    f32x4 sacc[2];
#pragma unroll
    for (int tm = 0; tm < 2; tm++)
#pragma unroll
        for (int r = 0; r < 4; r++) sacc[tm][r] = 0.f;

    for (int z = tid; z < 16 * 136 / 2; z += 256) ((unsigned int*)St)[z] = 0u;
    __syncthreads();

#pragma unroll 1
    for (int ch = 0; ch < 16; ch++) {
        int t0 = tb + ch * 64;

        // ---- P0: decay metadata (wave 0) ----
        if (tid < 64) {
            float x = gg[(size_t)(t0 + tid) * 32 + vh];
#pragma unroll
            for (int ofs = 1; ofs < 64; ofs <<= 1) {
                float up = __shfl_up(x, ofs, 64);
                if (tid >= ofs) x += up;
            }
            cc[tid] = x;
            lam[tid] = __expf(x);
            float tot = __shfl(x, 63, 64);
            ex64[tid] = __expf(tot - x);
            bet[tid] = bb[(size_t)(t0 + tid) * 32 + vh];
            if (tid == 0) lamT[0] = __expf(tot);
        }
        // ---- P1: K^T into LDS ----
#pragma unroll
        for (int rr = 0; rr < 4; rr++) {
            int idx = rr * 256 + tid;
            int tok = idx & 63, dkg = idx >> 6;  // 0..15
            const unsigned short* kr = kb + ((size_t)(t0 + tok) * 16 + hk) * 128 + dkg * 8;
            uint4 kv = *(const uint4*)kr;
            int base = (dkg * 8) * 72 + tok;
            Kt[base]       = (unsigned short)(kv.x & 0xffff);
            Kt[base + 72]  = (unsigned short)(kv.x >> 16);
            Kt[base + 144] = (unsigned short)(kv.y & 0xffff);
            Kt[base + 216] = (unsigned short)(kv.y >> 16);
            Kt[base + 288] = (unsigned short)(kv.z & 0xffff);
            Kt[base + 360] = (unsigned short)(kv.z >> 16);
            Kt[base + 432] = (unsigned short)(kv.w & 0xffff);
            Kt[base + 504] = (unsigned short)(kv.w >> 16);
        }
        __syncthreads();

        // ---- P2: [K;Q] K^T (A and P), frags direct from global ----
        {
            const unsigned short* src = (wv >= 2) ? qb : kb;
            f32x4 acc[2][4];
#pragma unroll
            for (int tm = 0; tm < 2; tm++)
#pragma unroll
                for (int tn = 0; tn < 4; tn++)
#pragma unroll
                    for (int r = 0; r < 4; r++) acc[tm][tn][r] = 0.f;
#pragma unroll
            for (int ks = 0; ks < 4; ks++) {
                bf16x8 af[2], bfr[4];
#pragma unroll
                for (int tm = 0; tm < 2; tm++) {
                    int row = rowb + tm * 16 + rc;
                    af[tm] = *(const bf16x8*)(src + ((size_t)(t0 + row) * 16 + hk) * 128 + ks * 32 + qd * 8);
                }
#pragma unroll
                for (int tn = 0; tn < 4; tn++) {
                    int row = tn * 16 + rc;
                    bfr[tn] = *(const bf16x8*)(kb + ((size_t)(t0 + row) * 16 + hk) * 128 + ks * 32 + qd * 8);
                }
#pragma unroll
                for (int tm = 0; tm < 2; tm++)
#pragma unroll
                    for (int tn = 0; tn < 4; tn++)
                        acc[tm][tn] = __builtin_amdgcn_mfma_f32_16x16x32_bf16(af[tm], bfr[tn], acc[tm][tn], 0, 0, 0);
            }
            if (wv < 2) {
#pragma unroll
                for (int tm = 0; tm < 2; tm++)
#pragma unroll
                    for (int tn = 0; tn < 4; tn++)
#pragma unroll
                        for (int r = 0; r < 4; r++) {
                            int i = rowb + tm * 16 + qd * 4 + r;
                            int j = tn * 16 + rc;
                            float val = acc[tm][tn][r];
                            float tv = 0.f;
                            if (i > j) tv = bet[i] * __expf(cc[i] - cc[j]) * val;
                            Tb[i * 72 + j] = f2bf(-tv);
                            if ((i >> 4) == (j >> 4) && i > j)
                                Td[(i >> 4) * 272 + (i & 15) * 17 + (j & 15)] = tv;
                        }
            } else {
#pragma unroll
                for (int tm = 0; tm < 2; tm++)
#pragma unroll
                    for (int tn = 0; tn < 4; tn++)
#pragma unroll
                        for (int r = 0; r < 4; r++) {
                            int i = rowb + tm * 16 + qd * 4 + r;
                            int j = tn * 16 + rc;
                            float ev = (i >= j) ? __expf(cc[i] - cc[j]) : 0.f;
                            Pb[i * 72 + j] = f2bf(ev * acc[tm][tn][r]);
                        }
            }
        }
        __syncthreads();

        // ---- P3: [K;Q] S0 ; RHS for waves 0/1, O-base for waves 2/3 ----
        f32x4 oacc[2];
        {
            const unsigned short* src = (wv >= 2) ? qb : kb;
            f32x4 acc[2];
#pragma unroll
            for (int tm = 0; tm < 2; tm++)
#pragma unroll
                for (int r = 0; r < 4; r++) acc[tm][r] = 0.f;
#pragma unroll
            for (int ks = 0; ks < 4; ks++) {
                bf16x8 af[2];
#pragma unroll
                for (int tm = 0; tm < 2; tm++) {
                    int row = rowb + tm * 16 + rc;
                    af[tm] = *(const bf16x8*)(src + ((size_t)(t0 + row) * 16 + hk) * 128 + ks * 32 + qd * 8);
                }
                bf16x8 bfr = *(const bf16x8*)&St[rc * 136 + ks * 32 + qd * 8];
#pragma unroll
                for (int tm = 0; tm < 2; tm++)
                    acc[tm] = __builtin_amdgcn_mfma_f32_16x16x32_bf16(af[tm], bfr, acc[tm], 0, 0, 0);
            }
            if (wv < 2) {
#pragma unroll
                for (int tm = 0; tm < 2; tm++)
#pragma unroll
                    for (int r = 0; r < 4; r++) {
                        int i = rowb + tm * 16 + qd * 4 + r;
                        float v = vv[((size_t)(t0 + i) * 32 + vh) * 128 + dvo + rc];
                        RHS[i * 17 + rc] = bet[i] * (v - lam[i] * acc[tm][r]);
                    }
            } else {
#pragma unroll
                for (int tm = 0; tm < 2; tm++)
#pragma unroll
                    for (int r = 0; r < 4; r++) {
                        int i = rowb + tm * 16 + qd * 4 + r;
                        oacc[tm][r] = lam[i] * acc[tm][r];
                    }
            }
        }
        for (int z = tid; z < 16 * 72 / 2; z += 256) ((unsigned int*)Dbt)[z] = 0u;
        __syncthreads();

        // ---- P4: blocked forward substitution (stage B -> wave B) ----
#pragma unroll
        for (int B = 0; B < 4; B++) {
            if (wv == B) {
                f32x4 tacc;
#pragma unroll
                for (int r = 0; r < 4; r++)
                    tacc[r] = RHS[(B * 16 + qd * 4 + r) * 17 + rc];
                const int nks = (B + 1) >> 1;  // 0,1,1,2
#pragma unroll
                for (int ks = 0; ks < 2; ks++) {
                    if (ks >= nks) break;
                    bf16x8 af = *(const bf16x8*)&Tb[(B * 16 + rc) * 72 + ks * 32 + qd * 8];
                    bf16x8 bf_ = *(const bf16x8*)&Dbt[rc * 72 + ks * 32 + qd * 8];
                    tacc = __builtin_amdgcn_mfma_f32_16x16x32_bf16(af, bf_, tacc, 0, 0, 0);
                }
#pragma unroll
                for (int r = 0; r < 4; r++)
                    RHS[(B * 16 + qd * 4 + r) * 17 + rc] = tacc[r];
                __builtin_amdgcn_s_waitcnt(0xc07f);  // lgkmcnt(0); wave-lockstep cross-lane LDS
                if (lane < 16) {
                    float d[16];
#pragma unroll
                    for (int i2 = 0; i2 < 16; i2++) d[i2] = RHS[(B * 16 + i2) * 17 + lane];
#pragma unroll
                    for (int i2 = 1; i2 < 16; i2++)
#pragma unroll
                        for (int j2 = 0; j2 < i2; j2++)
                            d[i2] -= Td[B * 272 + i2 * 17 + j2] * d[j2];
#pragma unroll
                    for (int i2 = 0; i2 < 16; i2++)
                        Dbt[lane * 72 + B * 16 + i2] = f2bf(d[i2]);
                }
            }
            __syncthreads();
        }

        // ---- P5: O += (E.P) Delta (waves 2,3) ; P6: S update (all waves) ----
        float l64 = lamT[0];
        if (wv >= 2) {
#pragma unroll
            for (int ks = 0; ks < 2; ks++) {
                bf16x8 af[2];
#pragma unroll
                for (int tm = 0; tm < 2; tm++)
                    af[tm] = *(const bf16x8*)&Pb[(rowb + tm * 16 + rc) * 72 + ks * 32 + qd * 8];
                bf16x8 bfr = *(const bf16x8*)&Dbt[rc * 72 + ks * 32 + qd * 8];
#pragma unroll
                for (int tm = 0; tm < 2; tm++)
                    oacc[tm] = __builtin_amdgcn_mfma_f32_16x16x32_bf16(af[tm], bfr, oacc[tm], 0, 0, 0);
            }
#pragma unroll
            for (int tm = 0; tm < 2; tm++)
#pragma unroll
                for (int r = 0; r < 4; r++) {
                    int i = rowb + tm * 16 + qd * 4 + r;
                    oo[((size_t)(t0 + i) * 32 + vh) * 128 + dvo + rc] = oacc[tm][r];
                }
        }
        {
#pragma unroll
            for (int tm = 0; tm < 2; tm++)
#pragma unroll
                for (int r = 0; r < 4; r++) sacc[tm][r] *= l64;
#pragma unroll
            for (int ks = 0; ks < 2; ks++) {
                float4 e0 = *(const float4*)&ex64[ks * 32 + qd * 8];
                float4 e1 = *(const float4*)&ex64[ks * 32 + qd * 8 + 4];
                bf16x8 braw = *(const bf16x8*)&Dbt[rc * 72 + ks * 32 + qd * 8];
                bf16x8 bs;
                bs[0] = (__bf16)((float)braw[0] * e0.x);
                bs[1] = (__bf16)((float)braw[1] * e0.y);
                bs[2] = (__bf16)((float)braw[2] * e0.z);
                bs[3] = (__bf16)((float)braw[3] * e0.w);
                bs[4] = (__bf16)((float)braw[4] * e1.x);
                bs[5] = (__bf16)((float)braw[5] * e1.y);
                bs[6] = (__bf16)((float)braw[6] * e1.z);
                bs[7] = (__bf16)((float)braw[7] * e1.w);
                bf16x8 af[2];
#pragma unroll
                for (int tm = 0; tm < 2; tm++)
                    af[tm] = *(const bf16x8*)&Kt[(wv * 32 + tm * 16 + rc) * 72 + ks * 32 + qd * 8];
#pragma unroll
                for (int tm = 0; tm < 2; tm++)
                    sacc[tm] = __builtin_amdgcn_mfma_f32_16x16x32_bf16(af[tm], bs, sacc[tm], 0, 0, 0);
            }
#pragma unroll
            for (int tm = 0; tm < 2; tm++)
#pragma unroll
                for (int r = 0; r < 4; r++) {
                    int dk = wv * 32 + tm * 16 + qd * 4 + r;
                    St[rc * 136 + dk] = f2bf(sacc[tm][r]);
                }
        }
        __syncthreads();
    }
}

// ---------------- gated RMSNorm + bf16 convert ----------------
__global__ __launch_bounds__(256) void norm_kernel(
    const float* __restrict__ oo, const unsigned short* __restrict__ qkvz,
    const float* __restrict__ norm_w, unsigned short* __restrict__ yb) {
    int w = threadIdx.x >> 6, lane = threadIdx.x & 63;
    int g = blockIdx.x * 4 + w;
    int t = g >> 5, vh = g & 31;
    size_t ob = (size_t)g * 128;
    size_t zb = (size_t)t * 12288 + (size_t)(vh >> 1) * 768 + 512 + (vh & 1) * 128;
    float x0 = oo[ob + lane], x1 = oo[ob + 64 + lane];
    float z0 = bf2f(qkvz[zb + lane]), z1 = bf2f(qkvz[zb + 64 + lane]);
    float xg0 = x0 * (z0 / (1.f + expf(-z0)));
    float xg1 = x1 * (z1 / (1.f + expf(-z1)));
    float s = xg0 * xg0 + xg1 * xg1;
    s += __shfl_xor(s, 1);
    s += __shfl_xor(s, 2);
    s += __shfl_xor(s, 4);
    s += __shfl_xor(s, 8);
    s += __shfl_xor(s, 16);
    s += __shfl_xor(s, 32);
    float r = rsqrtf(s * (1.f / 128.f) + 1e-6f);
    size_t y0 = (size_t)t * 4096 + (size_t)vh * 128;
    yb[y0 + lane] = f2bf(xg0 * r * norm_w[lane]);
    yb[y0 + 64 + lane] = f2bf(xg1 * r * norm_w[64 + lane]);
}

extern "C" void kernel_launch(void* const* d_in, const int* in_sizes, int n_in,
                              void* d_out, int out_size, void* d_ws, size_t ws_size,
                              hipStream_t stream) {
    const float* hs      = (const float*)d_in[0];
    const float* w_qkvz  = (const float*)d_in[1];
    const float* w_ba    = (const float*)d_in[2];
    const float* conv_w  = (const float*)d_in[3];
    const float* dt_bias = (const float*)d_in[4];
    const float* A_log   = (const float*)d_in[5];
    const float* norm_w  = (const float*)d_in[6];
    const float* w_out   = (const float*)d_in[7];
    float* out = (float*)d_out;
    (void)in_sizes; (void)n_in; (void)out_size; (void)ws_size;

    char* p = (char*)d_ws;
    auto alloc = [&](size_t b) { char* r = p; p += (b + 255) & ~(size_t)255; return r; };
    float* gg = (float*)alloc(2048ull * 32 * 4);                         // log-decay
    float* bb = (float*)alloc(2048ull * 32 * 4);                         // beta
    unsigned short* hsb  = (unsigned short*)alloc(2048ull * 2048 * 2);   // hs bf16
    unsigned short* wqT  = (unsigned short*)alloc(12288ull * 2048 * 2);  // w_qkvz^T bf16 [N,K]
    unsigned short* woT  = (unsigned short*)alloc(2048ull * 4096 * 2);   // w_out^T bf16 [N,K]
    unsigned short* qkvz = (unsigned short*)alloc(2048ull * 12288 * 2);  // projections bf16
    unsigned short* qb16 = (unsigned short*)alloc(2048ull * 2048 * 2);   // q normed bf16 [t,16,128]
    unsigned short* kb16 = (unsigned short*)alloc(2048ull * 2048 * 2);   // k normed bf16 [t,16,128]
    float* vv = (float*)alloc(2048ull * 4096 * 4);                       // v [t,32,128]
    float* oo = (float*)alloc(2048ull * 4096 * 4);                       // recurrence out
    unsigned short* yb = (unsigned short*)alloc(2048ull * 4096 * 2);     // normed, bf16

    cvt_bf16_kernel<<<4096, 256, 0, stream>>>(hs, hsb, 2048 * 2048 / 4);
    transpose_cvt_kernel<<<dim3(12288 / 32, 2048 / 32), 256, 0, stream>>>(w_qkvz, wqT, 2048, 12288);
    transpose_cvt_kernel<<<dim3(2048 / 32, 4096 / 32), 256, 0, stream>>>(w_out, woT, 4096, 2048);
    gemm_bt_kernel<1><<<dim3(96, 16), 256, 0, stream>>>(hsb, wqT, qkvz, 2048, 12288, 2048);
    bag_kernel<<<256, 256, 0, stream>>>(hs, w_ba, A_log, dt_bias, gg, bb);
    conv_kernel<<<2048, 256, 0, stream>>>(qkvz, conv_w, qb16, kb16, vv);
    rec_kernel<<<512, 256, 0, stream>>>(qb16, kb16, vv, gg, bb, oo);
    norm_kernel<<<16384, 256, 0, stream>>>(oo, qkvz, norm_w, yb);
    gemm_bt_kernel<0><<<dim3(16, 16), 256, 0, stream>>>(yb, woT, out, 2048, 2048, 4096);
}

// Round 6
// 784.635 us; speedup vs baseline: 1.8417x; 1.0803x over previous
//
#include <hip/hip_runtime.h>
#include <stdint.h>

#define AS1 __attribute__((address_space(1)))
#define AS3 __attribute__((address_space(3)))

typedef __bf16 bf16x8 __attribute__((ext_vector_type(8)));
typedef float f32x4 __attribute__((ext_vector_type(4)));

static __device__ __forceinline__ float bf2f(unsigned short u) {
    union { unsigned int i; float f; } x; x.i = ((unsigned int)u) << 16; return x.f;
}
static __device__ __forceinline__ unsigned short f2bf(float f) {
    union { float f; unsigned int i; } x; x.f = f;
    unsigned int u = x.i;
    unsigned int r = (u + 0x7fffu + ((u >> 16) & 1u)) >> 16;  // RNE
    return (unsigned short)r;
}

static __device__ __forceinline__ void gll16(const void* g, void* l) {
    __builtin_amdgcn_global_load_lds((const AS1 unsigned int*)g,
                                     (AS3 unsigned int*)l, 16, 0, 0);
}

// ---------------- f32 -> bf16 elementwise (vec4) ----------------
__global__ __launch_bounds__(256) void cvt_bf16_kernel(
    const float* __restrict__ src, unsigned short* __restrict__ dst, int n4) {
    int i = blockIdx.x * 256 + threadIdx.x;
    if (i >= n4) return;
    float4 v = ((const float4*)src)[i];
    ushort4 o;
    o.x = f2bf(v.x); o.y = f2bf(v.y); o.z = f2bf(v.z); o.w = f2bf(v.w);
    ((ushort4*)dst)[i] = o;
}

// ---------------- f32 [R,C] -> bf16 [C,R] transpose ----------------
__global__ __launch_bounds__(256) void transpose_cvt_kernel(
    const float* __restrict__ src, unsigned short* __restrict__ dst, int R, int C) {
    __shared__ float tile[32][33];
    int x = threadIdx.x & 31, y = threadIdx.x >> 5;
    int c0 = blockIdx.x * 32, r0 = blockIdx.y * 32;
#pragma unroll
    for (int i = 0; i < 4; i++)
        tile[y + i * 8][x] = src[(size_t)(r0 + y + i * 8) * C + (c0 + x)];
    __syncthreads();
#pragma unroll
    for (int i = 0; i < 4; i++)
        dst[(size_t)(c0 + y + i * 8) * R + (r0 + x)] = f2bf(tile[x][y + i * 8]);
}

// ---------------- bf16 MFMA GEMM: C[M,N] = A[M,K] * Bt[N,K]^T ----------------
template <int STORE_BF16>
__global__ __launch_bounds__(256) void gemm_bt_kernel(
    const unsigned short* __restrict__ A, const unsigned short* __restrict__ Bt,
    void* __restrict__ C, int M, int N, int K) {
    __shared__ __align__(16) unsigned short As[128 * 32];
    __shared__ __align__(16) unsigned short Bs[128 * 32];
    int tid = threadIdx.x;
    int lane = tid & 63;
    int w = tid >> 6;
    int m0 = blockIdx.y * 128;
    int n0 = blockIdx.x * 128;
    int qd = lane >> 4, rc = lane & 15;
    int wm = (w >> 1) * 64, wn = (w & 1) * 64;

    f32x4 acc[4][4];
#pragma unroll
    for (int i = 0; i < 4; i++)
#pragma unroll
        for (int j = 0; j < 4; j++)
#pragma unroll
            for (int r = 0; r < 4; r++) acc[i][j][r] = 0.f;

    int s0 = w * 128 + lane;
    int s1 = s0 + 64;
    int rA0 = s0 >> 2, cs0 = (s0 & 3) * 8;
    int rA1 = s1 >> 2, cs1 = (s1 & 3) * 8;
    const unsigned short* a0 = A + (size_t)(m0 + rA0) * K + cs0;
    const unsigned short* a1 = A + (size_t)(m0 + rA1) * K + cs1;
    const unsigned short* b0 = Bt + (size_t)(n0 + rA0) * K + cs0;
    const unsigned short* b1 = Bt + (size_t)(n0 + rA1) * K + cs1;
    unsigned short* lA0 = As + s0 * 8;
    unsigned short* lA1 = As + s1 * 8;
    unsigned short* lB0 = Bs + s0 * 8;
    unsigned short* lB1 = Bs + s1 * 8;

    for (int k0 = 0; k0 < K; k0 += 32) {
        __syncthreads();
        gll16(a0 + k0, lA0);
        gll16(a1 + k0, lA1);
        gll16(b0 + k0, lB0);
        gll16(b1 + k0, lB1);
        __syncthreads();
        bf16x8 af[4], bfr[4];
#pragma unroll
        for (int i = 0; i < 4; i++)
            af[i] = *(const bf16x8*)(As + (wm + i * 16 + rc) * 32 + qd * 8);
#pragma unroll
        for (int i = 0; i < 4; i++)
            bfr[i] = *(const bf16x8*)(Bs + (wn + i * 16 + rc) * 32 + qd * 8);
#pragma unroll
        for (int i = 0; i < 4; i++)
#pragma unroll
            for (int j = 0; j < 4; j++)
                acc[i][j] = __builtin_amdgcn_mfma_f32_16x16x32_bf16(af[i], bfr[j], acc[i][j], 0, 0, 0);
    }

#pragma unroll
    for (int i = 0; i < 4; i++)
#pragma unroll
        for (int j = 0; j < 4; j++)
#pragma unroll
            for (int r = 0; r < 4; r++) {
                int row = m0 + wm + i * 16 + qd * 4 + r;
                int col = n0 + wn + j * 16 + rc;
                if (STORE_BF16)
                    ((unsigned short*)C)[(size_t)row * N + col] = f2bf(acc[i][j][r]);
                else
                    ((float*)C)[(size_t)row * N + col] = acc[i][j][r];
            }
}

// ---------------- ba GEMM + beta/g computation ----------------
__global__ __launch_bounds__(256) void bag_kernel(
    const float* __restrict__ hs, const float* __restrict__ w_ba,
    const float* __restrict__ A_log, const float* __restrict__ dt_bias,
    float* __restrict__ gg, float* __restrict__ bb) {
    int w = threadIdx.x >> 6, lane = threadIdx.x & 63;
    int r0 = blockIdx.x * 8 + w * 2;
    const float* h0 = hs + (size_t)r0 * 2048;
    float a0 = 0.f, a1 = 0.f;
    for (int k = 0; k < 2048; k++) {
        float wv = w_ba[k * 64 + lane];
        a0 += h0[k] * wv;
        a1 += h0[2048 + k] * wv;
    }
    int h = lane >> 2, idx = lane & 3;
    int vh = h * 2 + (idx & 1);
    float accs[2] = {a0, a1};
#pragma unroll
    for (int j = 0; j < 2; j++) {
        int t = r0 + j;
        float acc = accs[j];
        if (idx < 2) {
            bb[t * 32 + vh] = 1.f / (1.f + expf(-acc));
        } else {
            float x = acc + dt_bias[vh];
            float sp = fmaxf(x, 0.f) + log1pf(expf(-fabsf(x)));
            gg[t * 32 + vh] = -expf(A_log[vh]) * sp;
        }
    }
}

// ---------------- depthwise causal conv(4) + silu + l2norm(q,k) ----------------
__global__ __launch_bounds__(256) void conv_kernel(
    const unsigned short* __restrict__ qkvz, const float* __restrict__ conv_w,
    unsigned short* __restrict__ qb, unsigned short* __restrict__ kb,
    float* __restrict__ vv) {
    __shared__ float xs[8192];
    __shared__ float rs[32];
    int t = blockIdx.x;
    int s = t & 1023;
    int tid = threadIdx.x;
    size_t rowbase = (size_t)t * 12288;
#pragma unroll
    for (int i = 0; i < 4; i++) {
        int c = (i * 256 + tid) * 8;
        int d = c & 127;
        int col;
        if (c < 2048) col = (c >> 7) * 768 + d;
        else if (c < 4096) col = ((c - 2048) >> 7) * 768 + 128 + d;
        else { int vh2 = (c - 4096) >> 7; col = (vh2 >> 1) * 768 + 256 + (vh2 & 1) * 128 + d; }
        float wts[8][4];
#pragma unroll
        for (int e = 0; e < 8; e++) {
            float4 t4 = *(const float4*)(conv_w + (size_t)(c + e) * 4);
            wts[e][0] = t4.x; wts[e][1] = t4.y; wts[e][2] = t4.z; wts[e][3] = t4.w;
        }
        float acc[8] = {0.f, 0.f, 0.f, 0.f, 0.f, 0.f, 0.f, 0.f};
#pragma unroll
        for (int j = 0; j < 4; j++) {
            int ss = s - 3 + j;
            if (ss >= 0) {
                uint4 u = *(const uint4*)(qkvz + rowbase + (size_t)(j - 3) * 12288 + col);
                const unsigned short* us = (const unsigned short*)&u;
#pragma unroll
                for (int e = 0; e < 8; e++) acc[e] += bf2f(us[e]) * wts[e][j];
            }
        }
#pragma unroll
        for (int e = 0; e < 8; e++) xs[c + e] = acc[e] / (1.f + expf(-acc[e]));
    }
    __syncthreads();
    {
        int seg = tid >> 3, part = tid & 7;
        const float* pp = xs + seg * 128 + part * 16;
        float s2 = 0.f;
#pragma unroll
        for (int j = 0; j < 16; j++) s2 += pp[j] * pp[j];
        s2 += __shfl_xor(s2, 1);
        s2 += __shfl_xor(s2, 2);
        s2 += __shfl_xor(s2, 4);
        if (part == 0) rs[seg] = rsqrtf(s2 + 1e-6f);
    }
    __syncthreads();
    const float QS = 0.08838834764831845f;  // 128^-0.5
#pragma unroll
    for (int i = 0; i < 4; i++) {
        int c = (i * 256 + tid) * 8;
        float x[8];
#pragma unroll
        for (int e = 0; e < 8; e++) x[e] = xs[c + e];
        if (c < 4096) {
            float sc = (c < 2048) ? rs[c >> 7] * QS : rs[((c - 2048) >> 7) + 16];
            uint4 o;
            o.x = (unsigned)f2bf(x[0] * sc) | ((unsigned)f2bf(x[1] * sc) << 16);
            o.y = (unsigned)f2bf(x[2] * sc) | ((unsigned)f2bf(x[3] * sc) << 16);
            o.z = (unsigned)f2bf(x[4] * sc) | ((unsigned)f2bf(x[5] * sc) << 16);
            o.w = (unsigned)f2bf(x[6] * sc) | ((unsigned)f2bf(x[7] * sc) << 16);
            if (c < 2048) *(uint4*)(qb + (size_t)t * 2048 + c) = o;
            else *(uint4*)(kb + (size_t)t * 2048 + c - 2048) = o;
        } else {
            float* vp = vv + (size_t)t * 4096 + c - 4096;
            *(float4*)vp = make_float4(x[0], x[1], x[2], x[3]);
            *(float4*)(vp + 4) = make_float4(x[4], x[5], x[6], x[7]);
        }
    }
}

// ---------------- delta-rule prep (parallel over 64 bh x 16 chunks) ----------------
// Per (bh, chunk): T = I + strict_lower(beta_i E_ij (KK^T)_ij), then solve
//   Dloc = T^{-1}(beta V)  and  W = T^{-1}(beta Lam K)  (256-col blocked FS),
// plus Pt = tril_incl(E o QK^T), KtT = Etil-folded K^T, lam/l64 metadata.
// No dependence on the running state S -> embarrassingly parallel.
__global__ __launch_bounds__(256, 2) void prep_kernel(
    const unsigned short* __restrict__ qb, const unsigned short* __restrict__ kb,
    const float* __restrict__ vv, const float* __restrict__ gg,
    const float* __restrict__ bb,
    unsigned short* __restrict__ Wg, unsigned short* __restrict__ DlT,
    unsigned short* __restrict__ KtT, unsigned short* __restrict__ Pt,
    float* __restrict__ lamg, float* __restrict__ l64g) {
    __shared__ __align__(16) unsigned short Ks[64 * 136];  // K rows bf16 (padded)
    __shared__ __align__(16) unsigned short Tb[64 * 72];   // -beta_i E_ij A_ij (i>j)
    __shared__ __align__(16) unsigned short Xb[64 * 72];   // batch solution [col][tok]
    __shared__ float Td[4 * 16 * 17];                      // +T diag blocks fp32
    __shared__ float RHS[64 * 68];                         // fp32 working RHS
    __shared__ float cc[64], bet[64], lam_s[64], ex64[64];

    int bid = blockIdx.x;            // bh*16 + ch
    int ch = bid & 15, bh = bid >> 4;
    int vh = bh & 31, b = bh >> 5;
    int hk = vh >> 1;
    int t0 = b * 1024 + ch * 64;
    int tid = threadIdx.x, wv = tid >> 6, lane = tid & 63;
    int qd = lane >> 4, rc = lane & 15;
    int rowb = (wv & 1) * 32;
    size_t obase = (size_t)bid * 8192;
    size_t pbase = (size_t)bid * 4096;

    // stage K rows [64][128] -> padded [64][136]
    {
        int tok = tid >> 2, seg = (tid & 3) * 32;
        const unsigned short* src = kb + ((size_t)(t0 + tok) * 16 + hk) * 128 + seg;
#pragma unroll
        for (int j = 0; j < 4; j++) {
            uint4 u = *(const uint4*)(src + j * 8);
            *(uint4*)&Ks[tok * 136 + seg + j * 8] = u;
        }
    }
    // decay metadata
    if (tid < 64) {
        float x = gg[(size_t)(t0 + tid) * 32 + vh];
#pragma unroll
        for (int ofs = 1; ofs < 64; ofs <<= 1) {
            float up = __shfl_up(x, ofs, 64);
            if (tid >= ofs) x += up;
        }
        cc[tid] = x;
        float l = __expf(x);
        lam_s[tid] = l;
        float tot = __shfl(x, 63, 64);
        ex64[tid] = __expf(tot - x);
        bet[tid] = bb[(size_t)(t0 + tid) * 32 + vh];
        lamg[(size_t)bid * 64 + tid] = l;
        if (tid == 0) l64g[bid] = __expf(tot);
    }
    __syncthreads();

    // A = K K^T (waves 0,1) -> Tb/Td ; P = Q K^T (waves 2,3) -> Pt (global)
    {
        f32x4 acc[2][4];
#pragma unroll
        for (int tm = 0; tm < 2; tm++)
#pragma unroll
            for (int tn = 0; tn < 4; tn++)
#pragma unroll
                for (int r = 0; r < 4; r++) acc[tm][tn][r] = 0.f;
#pragma unroll
        for (int ks = 0; ks < 4; ks++) {
            bf16x8 af[2], bfr[4];
#pragma unroll
            for (int tm = 0; tm < 2; tm++) {
                int row = rowb + tm * 16 + rc;
                if (wv < 2)
                    af[tm] = *(const bf16x8*)&Ks[row * 136 + ks * 32 + qd * 8];
                else
                    af[tm] = *(const bf16x8*)(qb + ((size_t)(t0 + row) * 16 + hk) * 128 + ks * 32 + qd * 8);
            }
#pragma unroll
            for (int tn = 0; tn < 4; tn++)
                bfr[tn] = *(const bf16x8*)&Ks[(tn * 16 + rc) * 136 + ks * 32 + qd * 8];
#pragma unroll
            for (int tm = 0; tm < 2; tm++)
#pragma unroll
                for (int tn = 0; tn < 4; tn++)
                    acc[tm][tn] = __builtin_amdgcn_mfma_f32_16x16x32_bf16(af[tm], bfr[tn], acc[tm][tn], 0, 0, 0);
        }
        if (wv < 2) {
#pragma unroll
            for (int tm = 0; tm < 2; tm++)
#pragma unroll
                for (int tn = 0; tn < 4; tn++)
#pragma unroll
                    for (int r = 0; r < 4; r++) {
                        int i = rowb + tm * 16 + qd * 4 + r;
                        int j = tn * 16 + rc;
                        float val = acc[tm][tn][r];
                        float tv = 0.f;
                        if (i > j) tv = bet[i] * __expf(cc[i] - cc[j]) * val;
                        Tb[i * 72 + j] = f2bf(-tv);
                        if ((i >> 4) == (j >> 4) && i > j)
                            Td[(i >> 4) * 272 + (i & 15) * 17 + (j & 15)] = tv;
                    }
        } else {
#pragma unroll
            for (int tm = 0; tm < 2; tm++)
#pragma unroll
                for (int tn = 0; tn < 4; tn++)
#pragma unroll
                    for (int r = 0; r < 4; r++) {
                        int i = rowb + tm * 16 + qd * 4 + r;
                        int j = tn * 16 + rc;
                        float ev = (i >= j) ? __expf(cc[i] - cc[j]) : 0.f;
                        Pt[pbase + i * 64 + j] = f2bf(ev * acc[tm][tn][r]);
                    }
        }
    }
    // KtT: Etil-folded K^T [dk][tok] (read-only on Ks/ex64, no barrier needed)
    {
        int dk = tid >> 1, half = tid & 1;
#pragma unroll
        for (int j = 0; j < 4; j++) {
            unsigned short tmp[8];
#pragma unroll
            for (int e = 0; e < 8; e++) {
                int tok = half * 32 + j * 8 + e;
                tmp[e] = f2bf(bf2f(Ks[tok * 136 + dk]) * ex64[tok]);
            }
            *(uint4*)(KtT + obase + dk * 64 + half * 32 + j * 8) = *(const uint4*)tmp;
        }
    }
    __syncthreads();

    // 4 column-batches of 64: solve T X = RHS (blocked forward substitution)
#pragma unroll 1
    for (int cb = 0; cb < 4; cb++) {
        for (int z = tid; z < 64 * 72 / 2; z += 256) ((unsigned int*)Xb)[z] = 0u;
        {
            int tok = tid >> 2, c0 = (tid & 3) * 16;
            if (cb < 2) {
                const float* vp = vv + ((size_t)(t0 + tok) * 32 + vh) * 128 + cb * 64 + c0;
                float bt = bet[tok];
#pragma unroll
                for (int j = 0; j < 4; j++) {
                    float4 v4 = *(const float4*)(vp + j * 4);
                    *(float4*)&RHS[tok * 68 + c0 + j * 4] =
                        make_float4(v4.x * bt, v4.y * bt, v4.z * bt, v4.w * bt);
                }
            } else {
                float bl = bet[tok] * lam_s[tok];
#pragma unroll
                for (int e = 0; e < 16; e++)
                    RHS[tok * 68 + c0 + e] = bl * bf2f(Ks[tok * 136 + (cb - 2) * 64 + c0 + e]);
            }
        }
        __syncthreads();
#pragma unroll
        for (int B = 0; B < 4; B++) {
            if (wv == B) {
                f32x4 tacc[4];
#pragma unroll
                for (int cf = 0; cf < 4; cf++)
#pragma unroll
                    for (int r = 0; r < 4; r++)
                        tacc[cf][r] = RHS[(B * 16 + qd * 4 + r) * 68 + cf * 16 + rc];
                const int nks = (B + 1) >> 1;  // 0,1,1,2
#pragma unroll
                for (int ks = 0; ks < 2; ks++) {
                    if (ks >= nks) break;
                    bf16x8 af = *(const bf16x8*)&Tb[(B * 16 + rc) * 72 + ks * 32 + qd * 8];
#pragma unroll
                    for (int cf = 0; cf < 4; cf++) {
                        bf16x8 bf_ = *(const bf16x8*)&Xb[(cf * 16 + rc) * 72 + ks * 32 + qd * 8];
                        tacc[cf] = __builtin_amdgcn_mfma_f32_16x16x32_bf16(af, bf_, tacc[cf], 0, 0, 0);
                    }
                }
#pragma unroll
                for (int cf = 0; cf < 4; cf++)
#pragma unroll
                    for (int r = 0; r < 4; r++)
                        RHS[(B * 16 + qd * 4 + r) * 68 + cf * 16 + rc] = tacc[cf][r];
                __builtin_amdgcn_s_waitcnt(0xc07f);  // lgkmcnt(0)
                {
                    float d[16];
#pragma unroll
                    for (int i2 = 0; i2 < 16; i2++) d[i2] = RHS[(B * 16 + i2) * 68 + lane];
#pragma unroll
                    for (int i2 = 1; i2 < 16; i2++)
#pragma unroll
                        for (int j2 = 0; j2 < i2; j2++)
                            d[i2] -= Td[B * 272 + i2 * 17 + j2] * d[j2];
#pragma unroll
                    for (int i2 = 0; i2 < 16; i2++)
                        Xb[lane * 72 + B * 16 + i2] = f2bf(d[i2]);
                }
            }
            __syncthreads();
        }
        // write out batch
        if (cb < 2) {  // Dloc^T rows [dv][tok], row-major copy
            int cl = tid >> 2, tq = (tid & 3) * 16;
#pragma unroll
            for (int j = 0; j < 2; j++) {
                uint4 u = *(const uint4*)&Xb[cl * 72 + tq + j * 8];
                *(uint4*)(DlT + obase + (cb * 64 + cl) * 64 + tq + j * 8) = u;
            }
        } else {  // W rows [tok][dk]: transpose from Xb
            int tok = tid & 63, dq = tid >> 6;
#pragma unroll
            for (int j = 0; j < 2; j++) {
                unsigned short tmp[8];
#pragma unroll
                for (int e = 0; e < 8; e++)
                    tmp[e] = Xb[(dq * 16 + j * 8 + e) * 72 + tok];
                *(uint4*)(Wg + obase + tok * 128 + (cb - 2) * 64 + dq * 16 + j * 8) = *(const uint4*)tmp;
            }
        }
        __syncthreads();
    }
}

// ---------------- serial inter-chunk scan (lean) ----------------
// grid 512 = (dv-slice:8 of 16)-major x (b:2) x (vh:32); block 256 = 4 waves.
// Per chunk: U^T = S0^T W^T; D' = Dloc - U (LDS RMW); O = Lam(Q S0) + Pt D';
// S <- l64 S + KtT D'. All frags from global (L2) or tiny LDS; 4 barriers.
__global__ __launch_bounds__(256, 2) void recb_kernel(
    const unsigned short* __restrict__ qb, const float* __restrict__ lamg,
    const float* __restrict__ l64g, const unsigned short* __restrict__ Wg,
    const unsigned short* __restrict__ DlT, const unsigned short* __restrict__ KtT,
    const unsigned short* __restrict__ Pt, float* __restrict__ oo) {
    __shared__ __align__(16) unsigned short St[16 * 136];  // S^T bf16 [dv][dk]
    __shared__ __align__(16) unsigned short Dls[16 * 72];  // Dloc^T -> D'^T slice
    int bid = blockIdx.x;
    int slice = bid >> 6;           // slice-major: same head -> same XCD
    int rest = bid & 63;
    int vh = rest & 31, b = rest >> 5;
    int bh = b * 32 + vh;
    int hk = vh >> 1, dvo = slice * 16, tb = b * 1024;
    int tid = threadIdx.x, wv = tid >> 6, lane = tid & 63;
    int qd = lane >> 4, rc = lane & 15;

    f32x4 sacc[2];
#pragma unroll
    for (int tm = 0; tm < 2; tm++)
#pragma unroll
        for (int r = 0; r < 4; r++) sacc[tm][r] = 0.f;
    for (int z = tid; z < 16 * 136 / 2; z += 256) ((unsigned int*)St)[z] = 0u;
    __syncthreads();

#pragma unroll 1
    for (int ch = 0; ch < 16; ch++) {
        int bhch = bh * 16 + ch;
        size_t obase = (size_t)bhch * 8192;
        size_t pbase = (size_t)bhch * 4096;
        int t0 = tb + ch * 64;
        // stage Dloc^T slice (16 rows x 64 toks)
        if (tid < 128) {
            int row = tid >> 3, t8 = (tid & 7) * 8;
            uint4 u = *(const uint4*)(DlT + obase + (dvo + row) * 64 + t8);
            *(uint4*)&Dls[row * 72 + t8] = u;
        }
        __syncthreads();
        // U^T = S0^T W^T ; RMW D' = Dloc - U
        {
            f32x4 uacc;
#pragma unroll
            for (int r = 0; r < 4; r++) uacc[r] = 0.f;
#pragma unroll
            for (int ks = 0; ks < 4; ks++) {
                bf16x8 a_ = *(const bf16x8*)&St[rc * 136 + ks * 32 + qd * 8];
                bf16x8 b_ = *(const bf16x8*)(Wg + obase + (size_t)(wv * 16 + rc) * 128 + ks * 32 + qd * 8);
                uacc = __builtin_amdgcn_mfma_f32_16x16x32_bf16(a_, b_, uacc, 0, 0, 0);
            }
#pragma unroll
            for (int r = 0; r < 4; r++) {
                int idx = (qd * 4 + r) * 72 + wv * 16 + rc;
                Dls[idx] = f2bf(bf2f(Dls[idx]) - uacc[r]);
            }
        }
        __syncthreads();
        // O = Lam(Q S0) + Pt D' ; S-update MFMA
        {
            f32x4 qacc;
#pragma unroll
            for (int r = 0; r < 4; r++) qacc[r] = 0.f;
#pragma unroll
            for (int ks = 0; ks < 4; ks++) {
                bf16x8 a_ = *(const bf16x8*)(qb + ((size_t)(t0 + wv * 16 + rc) * 16 + hk) * 128 + ks * 32 + qd * 8);
                bf16x8 b_ = *(const bf16x8*)&St[rc * 136 + ks * 32 + qd * 8];
                qacc = __builtin_amdgcn_mfma_f32_16x16x32_bf16(a_, b_, qacc, 0, 0, 0);
            }
            bf16x8 bd[2];
#pragma unroll
            for (int ks = 0; ks < 2; ks++)
                bd[ks] = *(const bf16x8*)&Dls[rc * 72 + ks * 32 + qd * 8];
            f32x4 oacc;
#pragma unroll
            for (int r = 0; r < 4; r++)
                oacc[r] = lamg[(size_t)bhch * 64 + wv * 16 + qd * 4 + r] * qacc[r];
#pragma unroll
            for (int ks = 0; ks < 2; ks++) {
                bf16x8 a_ = *(const bf16x8*)(Pt + pbase + (size_t)(wv * 16 + rc) * 64 + ks * 32 + qd * 8);
                oacc = __builtin_amdgcn_mfma_f32_16x16x32_bf16(a_, bd[ks], oacc, 0, 0, 0);
            }
#pragma unroll
            for (int r = 0; r < 4; r++)
                oo[((size_t)(t0 + wv * 16 + qd * 4 + r) * 32 + vh) * 128 + dvo + rc] = oacc[r];
            float l64 = l64g[bhch];
#pragma unroll
            for (int tm = 0; tm < 2; tm++) {
#pragma unroll
                for (int r = 0; r < 4; r++) sacc[tm][r] *= l64;
#pragma unroll
                for (int ks = 0; ks < 2; ks++) {
                    bf16x8 a_ = *(const bf16x8*)(KtT + obase + (size_t)(wv * 32 + tm * 16 + rc) * 64 + ks * 32 + qd * 8);
                    sacc[tm] = __builtin_amdgcn_mfma_f32_16x16x32_bf16(a_, bd[ks], sacc[tm], 0, 0, 0);
                }
            }
        }
        __syncthreads();
#pragma unroll
        for (int tm = 0; tm < 2; tm++)
#pragma unroll
            for (int r = 0; r < 4; r++)
                St[rc * 136 + wv * 32 + tm * 16 + qd * 4 + r] = f2bf(sacc[tm][r]);
        __syncthreads();
    }
}

// ---------------- gated RMSNorm + bf16 convert ----------------
__global__ __launch_bounds__(256) void norm_kernel(
    const float* __restrict__ oo, const unsigned short* __restrict__ qkvz,
    const float* __restrict__ norm_w, unsigned short* __restrict__ yb) {
    int w = threadIdx.x >> 6, lane = threadIdx.x & 63;
    int g = blockIdx.x * 4 + w;
    int t = g >> 5, vh = g & 31;
    size_t ob = (size_t)g * 128;
    size_t zb = (size_t)t * 12288 + (size_t)(vh >> 1) * 768 + 512 + (vh & 1) * 128;
    float x0 = oo[ob + lane], x1 = oo[ob + 64 + lane];
    float z0 = bf2f(qkvz[zb + lane]), z1 = bf2f(qkvz[zb + 64 + lane]);
    float xg0 = x0 * (z0 / (1.f + expf(-z0)));
    float xg1 = x1 * (z1 / (1.f + expf(-z1)));
    float s = xg0 * xg0 + xg1 * xg1;
    s += __shfl_xor(s, 1);
    s += __shfl_xor(s, 2);
    s += __shfl_xor(s, 4);
    s += __shfl_xor(s, 8);
    s += __shfl_xor(s, 16);
    s += __shfl_xor(s, 32);
    float r = rsqrtf(s * (1.f / 128.f) + 1e-6f);
    size_t y0 = (size_t)t * 4096 + (size_t)vh * 128;
    yb[y0 + lane] = f2bf(xg0 * r * norm_w[lane]);
    yb[y0 + 64 + lane] = f2bf(xg1 * r * norm_w[64 + lane]);
}

extern "C" void kernel_launch(void* const* d_in, const int* in_sizes, int n_in,
                              void* d_out, int out_size, void* d_ws, size_t ws_size,
                              hipStream_t stream) {
    const float* hs      = (const float*)d_in[0];
    const float* w_qkvz  = (const float*)d_in[1];
    const float* w_ba    = (const float*)d_in[2];
    const float* conv_w  = (const float*)d_in[3];
    const float* dt_bias = (const float*)d_in[4];
    const float* A_log   = (const float*)d_in[5];
    const float* norm_w  = (const float*)d_in[6];
    const float* w_out   = (const float*)d_in[7];
    float* out = (float*)d_out;
    (void)in_sizes; (void)n_in; (void)out_size; (void)ws_size;

    char* p = (char*)d_ws;
    auto alloc = [&](size_t b) { char* r = p; p += (b + 255) & ~(size_t)255; return r; };
    float* gg = (float*)alloc(2048ull * 32 * 4);                         // log-decay
    float* bb = (float*)alloc(2048ull * 32 * 4);                         // beta
    unsigned short* hsb  = (unsigned short*)alloc(2048ull * 2048 * 2);   // hs bf16
    unsigned short* wqT  = (unsigned short*)alloc(12288ull * 2048 * 2);  // w_qkvz^T bf16
    unsigned short* woT  = (unsigned short*)alloc(2048ull * 4096 * 2);   // w_out^T bf16
    unsigned short* qkvz = (unsigned short*)alloc(2048ull * 12288 * 2);  // projections bf16
    unsigned short* qb16 = (unsigned short*)alloc(2048ull * 2048 * 2);   // q normed bf16
    unsigned short* kb16 = (unsigned short*)alloc(2048ull * 2048 * 2);   // k normed bf16
    float* vv = (float*)alloc(2048ull * 4096 * 4);                       // v fp32
    float* oo = (float*)alloc(2048ull * 4096 * 4);                       // recurrence out
    unsigned short* yb = (unsigned short*)alloc(2048ull * 4096 * 2);     // normed bf16
    unsigned short* Wg  = (unsigned short*)alloc(1024ull * 8192 * 2);    // W [bhch][64][128]
    unsigned short* DlT = (unsigned short*)alloc(1024ull * 8192 * 2);    // Dloc^T [bhch][128][64]
    unsigned short* KtT = (unsigned short*)alloc(1024ull * 8192 * 2);    // Ktil^T [bhch][128][64]
    unsigned short* Pt  = (unsigned short*)alloc(1024ull * 4096 * 2);    // Ptil [bhch][64][64]
    float* lamg = (float*)alloc(1024ull * 64 * 4);                       // lambda per token
    float* l64g = (float*)alloc(1024ull * 4);                            // chunk decay

    cvt_bf16_kernel<<<4096, 256, 0, stream>>>(hs, hsb, 2048 * 2048 / 4);
    transpose_cvt_kernel<<<dim3(12288 / 32, 2048 / 32), 256, 0, stream>>>(w_qkvz, wqT, 2048, 12288);
    transpose_cvt_kernel<<<dim3(2048 / 32, 4096 / 32), 256, 0, stream>>>(w_out, woT, 4096, 2048);
    gemm_bt_kernel<1><<<dim3(96, 16), 256, 0, stream>>>(hsb, wqT, qkvz, 2048, 12288, 2048);
    bag_kernel<<<256, 256, 0, stream>>>(hs, w_ba, A_log, dt_bias, gg, bb);
    conv_kernel<<<2048, 256, 0, stream>>>(qkvz, conv_w, qb16, kb16, vv);
    prep_kernel<<<1024, 256, 0, stream>>>(qb16, kb16, vv, gg, bb, Wg, DlT, KtT, Pt, lamg, l64g);
    recb_kernel<<<512, 256, 0, stream>>>(qb16, lamg, l64g, Wg, DlT, KtT, Pt, oo);
    norm_kernel<<<16384, 256, 0, stream>>>(oo, qkvz, norm_w, yb);
    gemm_bt_kernel<0><<<dim3(16, 16), 256, 0, stream>>>(yb, woT, out, 2048, 2048, 4096);
}

// Round 7
// 761.548 us; speedup vs baseline: 1.8975x; 1.0303x over previous
//
#include <hip/hip_runtime.h>
#include <stdint.h>

#define AS1 __attribute__((address_space(1)))
#define AS3 __attribute__((address_space(3)))

typedef __bf16 bf16x8 __attribute__((ext_vector_type(8)));
typedef float f32x4 __attribute__((ext_vector_type(4)));

static __device__ __forceinline__ float bf2f(unsigned short u) {
    union { unsigned int i; float f; } x; x.i = ((unsigned int)u) << 16; return x.f;
}
static __device__ __forceinline__ unsigned short f2bf(float f) {
    union { float f; unsigned int i; } x; x.f = f;
    unsigned int u = x.i;
    unsigned int r = (u + 0x7fffu + ((u >> 16) & 1u)) >> 16;  // RNE
    return (unsigned short)r;
}

static __device__ __forceinline__ void gll16(const void* g, void* l) {
    __builtin_amdgcn_global_load_lds((const AS1 unsigned int*)g,
                                     (AS3 unsigned int*)l, 16, 0, 0);
}

// ---------------- f32 -> bf16 elementwise (vec4) ----------------
__global__ __launch_bounds__(256) void cvt_bf16_kernel(
    const float* __restrict__ src, unsigned short* __restrict__ dst, int n4) {
    int i = blockIdx.x * 256 + threadIdx.x;
    if (i >= n4) return;
    float4 v = ((const float4*)src)[i];
    ushort4 o;
    o.x = f2bf(v.x); o.y = f2bf(v.y); o.z = f2bf(v.z); o.w = f2bf(v.w);
    ((ushort4*)dst)[i] = o;
}

// ---------------- f32 [R,C] -> bf16 [C,R] transpose ----------------
__global__ __launch_bounds__(256) void transpose_cvt_kernel(
    const float* __restrict__ src, unsigned short* __restrict__ dst, int R, int C) {
    __shared__ float tile[32][33];
    int x = threadIdx.x & 31, y = threadIdx.x >> 5;
    int c0 = blockIdx.x * 32, r0 = blockIdx.y * 32;
#pragma unroll
    for (int i = 0; i < 4; i++)
        tile[y + i * 8][x] = src[(size_t)(r0 + y + i * 8) * C + (c0 + x)];
    __syncthreads();
#pragma unroll
    for (int i = 0; i < 4; i++)
        dst[(size_t)(c0 + y + i * 8) * R + (r0 + x)] = f2bf(tile[x][y + i * 8]);
}

// ---------------- bf16 MFMA GEMM: C = A[M,K] * Bt[N,K]^T ----------------
// blockIdx.z = K-slice (split-K): slice z covers k in [z*K/gz, (z+1)*K/gz),
// fp32 output goes to C + z*M*N (partials summed by add_out_kernel).
template <int STORE_BF16>
__global__ __launch_bounds__(256) void gemm_bt_kernel(
    const unsigned short* __restrict__ A, const unsigned short* __restrict__ Bt,
    void* __restrict__ C, int M, int N, int K) {
    __shared__ __align__(16) unsigned short As[128 * 32];
    __shared__ __align__(16) unsigned short Bs[128 * 32];
    int tid = threadIdx.x;
    int lane = tid & 63;
    int w = tid >> 6;
    int m0 = blockIdx.y * 128;
    int n0 = blockIdx.x * 128;
    int zz = blockIdx.z;
    int Kz = K / gridDim.z;
    int qd = lane >> 4, rc = lane & 15;
    int wm = (w >> 1) * 64, wn = (w & 1) * 64;

    f32x4 acc[4][4];
#pragma unroll
    for (int i = 0; i < 4; i++)
#pragma unroll
        for (int j = 0; j < 4; j++)
#pragma unroll
            for (int r = 0; r < 4; r++) acc[i][j][r] = 0.f;

    int s0 = w * 128 + lane;
    int s1 = s0 + 64;
    int rA0 = s0 >> 2, cs0 = (s0 & 3) * 8;
    int rA1 = s1 >> 2, cs1 = (s1 & 3) * 8;
    const unsigned short* a0 = A + (size_t)(m0 + rA0) * K + cs0 + (size_t)zz * Kz;
    const unsigned short* a1 = A + (size_t)(m0 + rA1) * K + cs1 + (size_t)zz * Kz;
    const unsigned short* b0 = Bt + (size_t)(n0 + rA0) * K + cs0 + (size_t)zz * Kz;
    const unsigned short* b1 = Bt + (size_t)(n0 + rA1) * K + cs1 + (size_t)zz * Kz;
    unsigned short* lA0 = As + s0 * 8;
    unsigned short* lA1 = As + s1 * 8;
    unsigned short* lB0 = Bs + s0 * 8;
    unsigned short* lB1 = Bs + s1 * 8;

    for (int k0 = 0; k0 < Kz; k0 += 32) {
        __syncthreads();
        gll16(a0 + k0, lA0);
        gll16(a1 + k0, lA1);
        gll16(b0 + k0, lB0);
        gll16(b1 + k0, lB1);
        __syncthreads();
        bf16x8 af[4], bfr[4];
#pragma unroll
        for (int i = 0; i < 4; i++)
            af[i] = *(const bf16x8*)(As + (wm + i * 16 + rc) * 32 + qd * 8);
#pragma unroll
        for (int i = 0; i < 4; i++)
            bfr[i] = *(const bf16x8*)(Bs + (wn + i * 16 + rc) * 32 + qd * 8);
#pragma unroll
        for (int i = 0; i < 4; i++)
#pragma unroll
            for (int j = 0; j < 4; j++)
                acc[i][j] = __builtin_amdgcn_mfma_f32_16x16x32_bf16(af[i], bfr[j], acc[i][j], 0, 0, 0);
    }

#pragma unroll
    for (int i = 0; i < 4; i++)
#pragma unroll
        for (int j = 0; j < 4; j++)
#pragma unroll
            for (int r = 0; r < 4; r++) {
                int row = m0 + wm + i * 16 + qd * 4 + r;
                int col = n0 + wn + j * 16 + rc;
                if (STORE_BF16)
                    ((unsigned short*)C)[(size_t)row * N + col] = f2bf(acc[i][j][r]);
                else
                    ((float*)C)[(size_t)zz * M * N + (size_t)row * N + col] = acc[i][j][r];
            }
}

// ---------------- split-K partial sum: out = p[0] + p[1] ----------------
__global__ __launch_bounds__(256) void add_out_kernel(
    const float* __restrict__ p, float* __restrict__ out, int n4) {
    int i = blockIdx.x * 256 + threadIdx.x;
    if (i >= n4) return;
    float4 a = ((const float4*)p)[i];
    float4 b = ((const float4*)(p + (size_t)n4 * 4))[i];
    ((float4*)out)[i] = make_float4(a.x + b.x, a.y + b.y, a.z + b.z, a.w + b.w);
}

// ---------------- ba GEMM + beta/g computation ----------------
__global__ __launch_bounds__(256) void bag_kernel(
    const float* __restrict__ hs, const float* __restrict__ w_ba,
    const float* __restrict__ A_log, const float* __restrict__ dt_bias,
    float* __restrict__ gg, float* __restrict__ bb) {
    int w = threadIdx.x >> 6, lane = threadIdx.x & 63;
    int r0 = blockIdx.x * 8 + w * 2;
    const float* h0 = hs + (size_t)r0 * 2048;
    float a0 = 0.f, a1 = 0.f;
    for (int k = 0; k < 2048; k++) {
        float wv = w_ba[k * 64 + lane];
        a0 += h0[k] * wv;
        a1 += h0[2048 + k] * wv;
    }
    int h = lane >> 2, idx = lane & 3;
    int vh = h * 2 + (idx & 1);
    float accs[2] = {a0, a1};
#pragma unroll
    for (int j = 0; j < 2; j++) {
        int t = r0 + j;
        float acc = accs[j];
        if (idx < 2) {
            bb[t * 32 + vh] = 1.f / (1.f + expf(-acc));
        } else {
            float x = acc + dt_bias[vh];
            float sp = fmaxf(x, 0.f) + log1pf(expf(-fabsf(x)));
            gg[t * 32 + vh] = -expf(A_log[vh]) * sp;
        }
    }
}

// ---------------- depthwise causal conv(4) + silu + l2norm(q,k) ----------------
__global__ __launch_bounds__(256) void conv_kernel(
    const unsigned short* __restrict__ qkvz, const float* __restrict__ conv_w,
    unsigned short* __restrict__ qb, unsigned short* __restrict__ kb,
    float* __restrict__ vv) {
    __shared__ float xs[8192];
    __shared__ float rs[32];
    int t = blockIdx.x;
    int s = t & 1023;
    int tid = threadIdx.x;
    size_t rowbase = (size_t)t * 12288;
#pragma unroll
    for (int i = 0; i < 4; i++) {
        int c = (i * 256 + tid) * 8;
        int d = c & 127;
        int col;
        if (c < 2048) col = (c >> 7) * 768 + d;
        else if (c < 4096) col = ((c - 2048) >> 7) * 768 + 128 + d;
        else { int vh2 = (c - 4096) >> 7; col = (vh2 >> 1) * 768 + 256 + (vh2 & 1) * 128 + d; }
        float wts[8][4];
#pragma unroll
        for (int e = 0; e < 8; e++) {
            float4 t4 = *(const float4*)(conv_w + (size_t)(c + e) * 4);
            wts[e][0] = t4.x; wts[e][1] = t4.y; wts[e][2] = t4.z; wts[e][3] = t4.w;
        }
        float acc[8] = {0.f, 0.f, 0.f, 0.f, 0.f, 0.f, 0.f, 0.f};
#pragma unroll
        for (int j = 0; j < 4; j++) {
            int ss = s - 3 + j;
            if (ss >= 0) {
                uint4 u = *(const uint4*)(qkvz + rowbase + (size_t)(j - 3) * 12288 + col);
                const unsigned short* us = (const unsigned short*)&u;
#pragma unroll
                for (int e = 0; e < 8; e++) acc[e] += bf2f(us[e]) * wts[e][j];
            }
        }
#pragma unroll
        for (int e = 0; e < 8; e++) xs[c + e] = acc[e] / (1.f + expf(-acc[e]));
    }
    __syncthreads();
    {
        int seg = tid >> 3, part = tid & 7;
        const float* pp = xs + seg * 128 + part * 16;
        float s2 = 0.f;
#pragma unroll
        for (int j = 0; j < 16; j++) s2 += pp[j] * pp[j];
        s2 += __shfl_xor(s2, 1);
        s2 += __shfl_xor(s2, 2);
        s2 += __shfl_xor(s2, 4);
        if (part == 0) rs[seg] = rsqrtf(s2 + 1e-6f);
    }
    __syncthreads();
    const float QS = 0.08838834764831845f;  // 128^-0.5
#pragma unroll
    for (int i = 0; i < 4; i++) {
        int c = (i * 256 + tid) * 8;
        float x[8];
#pragma unroll
        for (int e = 0; e < 8; e++) x[e] = xs[c + e];
        if (c < 4096) {
            float sc = (c < 2048) ? rs[c >> 7] * QS : rs[((c - 2048) >> 7) + 16];
            uint4 o;
            o.x = (unsigned)f2bf(x[0] * sc) | ((unsigned)f2bf(x[1] * sc) << 16);
            o.y = (unsigned)f2bf(x[2] * sc) | ((unsigned)f2bf(x[3] * sc) << 16);
            o.z = (unsigned)f2bf(x[4] * sc) | ((unsigned)f2bf(x[5] * sc) << 16);
            o.w = (unsigned)f2bf(x[6] * sc) | ((unsigned)f2bf(x[7] * sc) << 16);
            if (c < 2048) *(uint4*)(qb + (size_t)t * 2048 + c) = o;
            else *(uint4*)(kb + (size_t)t * 2048 + c - 2048) = o;
        } else {
            float* vp = vv + (size_t)t * 4096 + c - 4096;
            *(float4*)vp = make_float4(x[0], x[1], x[2], x[3]);
            *(float4*)(vp + 4) = make_float4(x[4], x[5], x[6], x[7]);
        }
    }
}

// ---------------- delta-rule prep (parallel over 64 bh x 16 chunks) ----------------
// Rewritten FS: the 4 col-batches of T^{-1}[betaV | betaLamK] are independent ->
// one batch per wave, barrier-free forward substitution (2 barriers/block total,
// no idle waves). K fragments come straight from global (L2-hot), no Ks staging.
__global__ __launch_bounds__(256, 2) void prep_kernel(
    const unsigned short* __restrict__ qb, const unsigned short* __restrict__ kb,
    const float* __restrict__ vv, const float* __restrict__ gg,
    const float* __restrict__ bb,
    unsigned short* __restrict__ Wg, unsigned short* __restrict__ DlT,
    unsigned short* __restrict__ KtT, unsigned short* __restrict__ Pt,
    float* __restrict__ lamg, float* __restrict__ l64g) {
    __shared__ __align__(16) unsigned short Tb[64 * 72];    // -beta_i E_ij A_ij (i>j)
    __shared__ __align__(16) unsigned short Xw[4][64 * 72]; // per-wave solutions [col][tok]
    __shared__ float Td[4 * 16 * 17];                       // +T diag blocks fp32
    __shared__ float RHSw[4][16 * 68];                      // per-wave stage scratch
    __shared__ float cc[64], bet[64], lam_s[64], ex64[64];

    int bid = blockIdx.x;            // bh*16 + ch
    int ch = bid & 15, bh = bid >> 4;
    int vh = bh & 31, b = bh >> 5;
    int hk = vh >> 1;
    int t0 = b * 1024 + ch * 64;
    int tid = threadIdx.x, wv = tid >> 6, lane = tid & 63;
    int qd = lane >> 4, rc = lane & 15;
    int rowb = (wv & 1) * 32;
    size_t obase = (size_t)bid * 8192;
    size_t pbase = (size_t)bid * 4096;

    // decay metadata (wave 0)
    if (tid < 64) {
        float x = gg[(size_t)(t0 + tid) * 32 + vh];
#pragma unroll
        for (int ofs = 1; ofs < 64; ofs <<= 1) {
            float up = __shfl_up(x, ofs, 64);
            if (tid >= ofs) x += up;
        }
        cc[tid] = x;
        float l = __expf(x);
        lam_s[tid] = l;
        float tot = __shfl(x, 63, 64);
        ex64[tid] = __expf(tot - x);
        bet[tid] = bb[(size_t)(t0 + tid) * 32 + vh];
        lamg[(size_t)bid * 64 + tid] = l;
        if (tid == 0) l64g[bid] = __expf(tot);
    }
    __syncthreads();

    // phase A: A = K K^T (waves 0,1) -> Tb/Td ; P = Q K^T (waves 2,3) -> Pt
    {
        const unsigned short* src = (wv >= 2) ? qb : kb;
        f32x4 acc[2][4];
#pragma unroll
        for (int tm = 0; tm < 2; tm++)
#pragma unroll
            for (int tn = 0; tn < 4; tn++)
#pragma unroll
                for (int r = 0; r < 4; r++) acc[tm][tn][r] = 0.f;
#pragma unroll
        for (int ks = 0; ks < 4; ks++) {
            bf16x8 af[2], bfr[4];
#pragma unroll
            for (int tm = 0; tm < 2; tm++) {
                int row = rowb + tm * 16 + rc;
                af[tm] = *(const bf16x8*)(src + ((size_t)(t0 + row) * 16 + hk) * 128 + ks * 32 + qd * 8);
            }
#pragma unroll
            for (int tn = 0; tn < 4; tn++)
                bfr[tn] = *(const bf16x8*)(kb + ((size_t)(t0 + tn * 16 + rc) * 16 + hk) * 128 + ks * 32 + qd * 8);
#pragma unroll
            for (int tm = 0; tm < 2; tm++)
#pragma unroll
                for (int tn = 0; tn < 4; tn++)
                    acc[tm][tn] = __builtin_amdgcn_mfma_f32_16x16x32_bf16(af[tm], bfr[tn], acc[tm][tn], 0, 0, 0);
        }
        if (wv < 2) {
#pragma unroll
            for (int tm = 0; tm < 2; tm++)
#pragma unroll
                for (int tn = 0; tn < 4; tn++)
#pragma unroll
                    for (int r = 0; r < 4; r++) {
                        int i = rowb + tm * 16 + qd * 4 + r;
                        int j = tn * 16 + rc;
                        float val = acc[tm][tn][r];
                        float tv = 0.f;
                        if (i > j) tv = bet[i] * __expf(cc[i] - cc[j]) * val;
                        Tb[i * 72 + j] = f2bf(-tv);
                        if ((i >> 4) == (j >> 4) && i > j)
                            Td[(i >> 4) * 272 + (i & 15) * 17 + (j & 15)] = tv;
                    }
        } else {
#pragma unroll
            for (int tm = 0; tm < 2; tm++)
#pragma unroll
                for (int tn = 0; tn < 4; tn++)
#pragma unroll
                    for (int r = 0; r < 4; r++) {
                        int i = rowb + tm * 16 + qd * 4 + r;
                        int j = tn * 16 + rc;
                        float ev = (i >= j) ? __expf(cc[i] - cc[j]) : 0.f;
                        Pt[pbase + i * 64 + j] = f2bf(ev * acc[tm][tn][r]);
                    }
        }
    }
    // KtT: Etil-folded K^T [dk][tok] straight from global (L2-hot)
    {
        int dk = tid >> 1, half = tid & 1;
#pragma unroll
        for (int j = 0; j < 4; j++) {
            unsigned short tmp[8];
#pragma unroll
            for (int e = 0; e < 8; e++) {
                int tok = half * 32 + j * 8 + e;
                tmp[e] = f2bf(bf2f(kb[((size_t)(t0 + tok) * 16 + hk) * 128 + dk]) * ex64[tok]);
            }
            *(uint4*)(KtT + obase + dk * 64 + half * 32 + j * 8) = *(const uint4*)tmp;
        }
    }
    __syncthreads();   // Tb/Td ready for all waves

    // per-wave forward substitution: wave wv owns col-batch cb = wv (64 cols)
    {
        int cb = wv;
        unsigned short* Xb = Xw[wv];
        float* RHS = RHSw[wv];
        for (int z = lane; z < 64 * 72 / 2; z += 64) ((unsigned int*)Xb)[z] = 0u;
#pragma unroll
        for (int B = 0; B < 4; B++) {
            f32x4 tacc[4];
#pragma unroll
            for (int cf = 0; cf < 4; cf++)
#pragma unroll
                for (int r = 0; r < 4; r++) {
                    int i = B * 16 + qd * 4 + r;
                    int c = cf * 16 + rc;
                    float v;
                    if (cb < 2)
                        v = bet[i] * vv[((size_t)(t0 + i) * 32 + vh) * 128 + cb * 64 + c];
                    else
                        v = bet[i] * lam_s[i] * bf2f(kb[((size_t)(t0 + i) * 16 + hk) * 128 + (cb - 2) * 64 + c]);
                    tacc[cf][r] = v;
                }
            __builtin_amdgcn_s_waitcnt(0xc07f);  // prior Xb writes (same wave) visible
            const int nks = (B + 1) >> 1;  // 0,1,1,2
#pragma unroll
            for (int ks = 0; ks < 2; ks++) {
                if (ks >= nks) break;
                bf16x8 af = *(const bf16x8*)&Tb[(B * 16 + rc) * 72 + ks * 32 + qd * 8];
#pragma unroll
                for (int cf = 0; cf < 4; cf++) {
                    bf16x8 bf_ = *(const bf16x8*)&Xb[(cf * 16 + rc) * 72 + ks * 32 + qd * 8];
                    tacc[cf] = __builtin_amdgcn_mfma_f32_16x16x32_bf16(af, bf_, tacc[cf], 0, 0, 0);
                }
            }
#pragma unroll
            for (int cf = 0; cf < 4; cf++)
#pragma unroll
                for (int r = 0; r < 4; r++)
                    RHS[(qd * 4 + r) * 68 + cf * 16 + rc] = tacc[cf][r];
            __builtin_amdgcn_s_waitcnt(0xc07f);  // RHS visible for transposed read
            {
                float d[16];
#pragma unroll
                for (int i2 = 0; i2 < 16; i2++) d[i2] = RHS[i2 * 68 + lane];
#pragma unroll
                for (int i2 = 1; i2 < 16; i2++)
#pragma unroll
                    for (int j2 = 0; j2 < i2; j2++)
                        d[i2] -= Td[B * 272 + i2 * 17 + j2] * d[j2];
#pragma unroll
                for (int i2 = 0; i2 < 16; i2++)
                    Xb[lane * 72 + B * 16 + i2] = f2bf(d[i2]);
            }
        }
        __builtin_amdgcn_s_waitcnt(0xc07f);
        // write out this wave's batch
        if (cb < 2) {  // Dloc^T rows [dv = cb*64+lane][tok]
#pragma unroll
            for (int j = 0; j < 8; j++) {
                uint4 u = *(const uint4*)&Xb[lane * 72 + j * 8];
                *(uint4*)(DlT + obase + (size_t)(cb * 64 + lane) * 64 + j * 8) = u;
            }
        } else {  // W rows [tok = lane][dk]: transpose from Xb
#pragma unroll
            for (int dq = 0; dq < 8; dq++) {
                unsigned short tmp[8];
#pragma unroll
                for (int e = 0; e < 8; e++)
                    tmp[e] = Xb[(dq * 8 + e) * 72 + lane];
                *(uint4*)(Wg + obase + (size_t)lane * 128 + (cb - 2) * 64 + dq * 8) = *(const uint4*)tmp;
            }
        }
    }
}

// ---------------- serial inter-chunk scan (lean) ----------------
__global__ __launch_bounds__(256, 2) void recb_kernel(
    const unsigned short* __restrict__ qb, const float* __restrict__ lamg,
    const float* __restrict__ l64g, const unsigned short* __restrict__ Wg,
    const unsigned short* __restrict__ DlT, const unsigned short* __restrict__ KtT,
    const unsigned short* __restrict__ Pt, float* __restrict__ oo) {
    __shared__ __align__(16) unsigned short St[16 * 136];  // S^T bf16 [dv][dk]
    __shared__ __align__(16) unsigned short Dls[16 * 72];  // Dloc^T -> D'^T slice
    int bid = blockIdx.x;
    int slice = bid >> 6;           // slice-major: same head -> same XCD
    int rest = bid & 63;
    int vh = rest & 31, b = rest >> 5;
    int bh = b * 32 + vh;
    int hk = vh >> 1, dvo = slice * 16, tb = b * 1024;
    int tid = threadIdx.x, wv = tid >> 6, lane = tid & 63;
    int qd = lane >> 4, rc = lane & 15;

    f32x4 sacc[2];
#pragma unroll
    for (int tm = 0; tm < 2; tm++)
#pragma unroll
        for (int r = 0; r < 4; r++) sacc[tm][r] = 0.f;
    for (int z = tid; z < 16 * 136 / 2; z += 256) ((unsigned int*)St)[z] = 0u;
    __syncthreads();

#pragma unroll 1
    for (int ch = 0; ch < 16; ch++) {
        int bhch = bh * 16 + ch;
        size_t obase = (size_t)bhch * 8192;
        size_t pbase = (size_t)bhch * 4096;
        int t0 = tb + ch * 64;
        if (tid < 128) {
            int row = tid >> 3, t8 = (tid & 7) * 8;
            uint4 u = *(const uint4*)(DlT + obase + (dvo + row) * 64 + t8);
            *(uint4*)&Dls[row * 72 + t8] = u;
        }
        __syncthreads();
        {
            f32x4 uacc;
#pragma unroll
            for (int r = 0; r < 4; r++) uacc[r] = 0.f;
#pragma unroll
            for (int ks = 0; ks < 4; ks++) {
                bf16x8 a_ = *(const bf16x8*)&St[rc * 136 + ks * 32 + qd * 8];
                bf16x8 b_ = *(const bf16x8*)(Wg + obase + (size_t)(wv * 16 + rc) * 128 + ks * 32 + qd * 8);
                uacc = __builtin_amdgcn_mfma_f32_16x16x32_bf16(a_, b_, uacc, 0, 0, 0);
            }
#pragma unroll
            for (int r = 0; r < 4; r++) {
                int idx = (qd * 4 + r) * 72 + wv * 16 + rc;
                Dls[idx] = f2bf(bf2f(Dls[idx]) - uacc[r]);
            }
        }
        __syncthreads();
        {
            f32x4 qacc;
#pragma unroll
            for (int r = 0; r < 4; r++) qacc[r] = 0.f;
#pragma unroll
            for (int ks = 0; ks < 4; ks++) {
                bf16x8 a_ = *(const bf16x8*)(qb + ((size_t)(t0 + wv * 16 + rc) * 16 + hk) * 128 + ks * 32 + qd * 8);
                bf16x8 b_ = *(const bf16x8*)&St[rc * 136 + ks * 32 + qd * 8];
                qacc = __builtin_amdgcn_mfma_f32_16x16x32_bf16(a_, b_, qacc, 0, 0, 0);
            }
            bf16x8 bd[2];
#pragma unroll
            for (int ks = 0; ks < 2; ks++)
                bd[ks] = *(const bf16x8*)&Dls[rc * 72 + ks * 32 + qd * 8];
            f32x4 oacc;
#pragma unroll
            for (int r = 0; r < 4; r++)
                oacc[r] = lamg[(size_t)bhch * 64 + wv * 16 + qd * 4 + r] * qacc[r];
#pragma unroll
            for (int ks = 0; ks < 2; ks++) {
                bf16x8 a_ = *(const bf16x8*)(Pt + pbase + (size_t)(wv * 16 + rc) * 64 + ks * 32 + qd * 8);
                oacc = __builtin_amdgcn_mfma_f32_16x16x32_bf16(a_, bd[ks], oacc, 0, 0, 0);
            }
#pragma unroll
            for (int r = 0; r < 4; r++)
                oo[((size_t)(t0 + wv * 16 + qd * 4 + r) * 32 + vh) * 128 + dvo + rc] = oacc[r];
            float l64 = l64g[bhch];
#pragma unroll
            for (int tm = 0; tm < 2; tm++) {
#pragma unroll
                for (int r = 0; r < 4; r++) sacc[tm][r] *= l64;
#pragma unroll
                for (int ks = 0; ks < 2; ks++) {
                    bf16x8 a_ = *(const bf16x8*)(KtT + obase + (size_t)(wv * 32 + tm * 16 + rc) * 64 + ks * 32 + qd * 8);
                    sacc[tm] = __builtin_amdgcn_mfma_f32_16x16x32_bf16(a_, bd[ks], sacc[tm], 0, 0, 0);
                }
            }
        }
        __syncthreads();
#pragma unroll
        for (int tm = 0; tm < 2; tm++)
#pragma unroll
            for (int r = 0; r < 4; r++)
                St[rc * 136 + wv * 32 + tm * 16 + qd * 4 + r] = f2bf(sacc[tm][r]);
        __syncthreads();
    }
}

// ---------------- gated RMSNorm + bf16 convert ----------------
__global__ __launch_bounds__(256) void norm_kernel(
    const float* __restrict__ oo, const unsigned short* __restrict__ qkvz,
    const float* __restrict__ norm_w, unsigned short* __restrict__ yb) {
    int w = threadIdx.x >> 6, lane = threadIdx.x & 63;
    int g = blockIdx.x * 4 + w;
    int t = g >> 5, vh = g & 31;
    size_t ob = (size_t)g * 128;
    size_t zb = (size_t)t * 12288 + (size_t)(vh >> 1) * 768 + 512 + (vh & 1) * 128;
    float x0 = oo[ob + lane], x1 = oo[ob + 64 + lane];
    float z0 = bf2f(qkvz[zb + lane]), z1 = bf2f(qkvz[zb + 64 + lane]);
    float xg0 = x0 * (z0 / (1.f + expf(-z0)));
    float xg1 = x1 * (z1 / (1.f + expf(-z1)));
    float s = xg0 * xg0 + xg1 * xg1;
    s += __shfl_xor(s, 1);
    s += __shfl_xor(s, 2);
    s += __shfl_xor(s, 4);
    s += __shfl_xor(s, 8);
    s += __shfl_xor(s, 16);
    s += __shfl_xor(s, 32);
    float r = rsqrtf(s * (1.f / 128.f) + 1e-6f);
    size_t y0 = (size_t)t * 4096 + (size_t)vh * 128;
    yb[y0 + lane] = f2bf(xg0 * r * norm_w[lane]);
    yb[y0 + 64 + lane] = f2bf(xg1 * r * norm_w[64 + lane]);
}

extern "C" void kernel_launch(void* const* d_in, const int* in_sizes, int n_in,
                              void* d_out, int out_size, void* d_ws, size_t ws_size,
                              hipStream_t stream) {
    const float* hs      = (const float*)d_in[0];
    const float* w_qkvz  = (const float*)d_in[1];
    const float* w_ba    = (const float*)d_in[2];
    const float* conv_w  = (const float*)d_in[3];
    const float* dt_bias = (const float*)d_in[4];
    const float* A_log   = (const float*)d_in[5];
    const float* norm_w  = (const float*)d_in[6];
    const float* w_out   = (const float*)d_in[7];
    float* out = (float*)d_out;
    (void)in_sizes; (void)n_in; (void)out_size; (void)ws_size;

    char* p = (char*)d_ws;
    auto alloc = [&](size_t b) { char* r = p; p += (b + 255) & ~(size_t)255; return r; };
    float* gg = (float*)alloc(2048ull * 32 * 4);                         // log-decay
    float* bb = (float*)alloc(2048ull * 32 * 4);                         // beta
    unsigned short* hsb  = (unsigned short*)alloc(2048ull * 2048 * 2);   // hs bf16
    unsigned short* wqT  = (unsigned short*)alloc(12288ull * 2048 * 2);  // w_qkvz^T bf16
    unsigned short* woT  = (unsigned short*)alloc(2048ull * 4096 * 2);   // w_out^T bf16
    unsigned short* qkvz = (unsigned short*)alloc(2048ull * 12288 * 2);  // projections bf16
    unsigned short* qb16 = (unsigned short*)alloc(2048ull * 2048 * 2);   // q normed bf16
    unsigned short* kb16 = (unsigned short*)alloc(2048ull * 2048 * 2);   // k normed bf16
    float* vv = (float*)alloc(2048ull * 4096 * 4);                       // v fp32
    float* oo = (float*)alloc(2048ull * 4096 * 4);                       // recurrence out
    unsigned short* yb = (unsigned short*)alloc(2048ull * 4096 * 2);     // normed bf16
    unsigned short* Wg  = (unsigned short*)alloc(1024ull * 8192 * 2);    // W [bhch][64][128]
    unsigned short* DlT = (unsigned short*)alloc(1024ull * 8192 * 2);    // Dloc^T [bhch][128][64]
    unsigned short* KtT = (unsigned short*)alloc(1024ull * 8192 * 2);    // Ktil^T [bhch][128][64]
    unsigned short* Pt  = (unsigned short*)alloc(1024ull * 4096 * 2);    // Ptil [bhch][64][64]
    float* lamg = (float*)alloc(1024ull * 64 * 4);                       // lambda per token
    float* l64g = (float*)alloc(1024ull * 4);                            // chunk decay
    // gemm2 split-K partials reuse wqT's 50 MB (dead after gemm1); need 33.6 MB
    float* gpart = (float*)wqT;

    cvt_bf16_kernel<<<4096, 256, 0, stream>>>(hs, hsb, 2048 * 2048 / 4);
    transpose_cvt_kernel<<<dim3(12288 / 32, 2048 / 32), 256, 0, stream>>>(w_qkvz, wqT, 2048, 12288);
    transpose_cvt_kernel<<<dim3(2048 / 32, 4096 / 32), 256, 0, stream>>>(w_out, woT, 4096, 2048);
    gemm_bt_kernel<1><<<dim3(96, 16, 1), 256, 0, stream>>>(hsb, wqT, qkvz, 2048, 12288, 2048);
    bag_kernel<<<256, 256, 0, stream>>>(hs, w_ba, A_log, dt_bias, gg, bb);
    conv_kernel<<<2048, 256, 0, stream>>>(qkvz, conv_w, qb16, kb16, vv);
    prep_kernel<<<1024, 256, 0, stream>>>(qb16, kb16, vv, gg, bb, Wg, DlT, KtT, Pt, lamg, l64g);
    recb_kernel<<<512, 256, 0, stream>>>(qb16, lamg, l64g, Wg, DlT, KtT, Pt, oo);
    norm_kernel<<<16384, 256, 0, stream>>>(oo, qkvz, norm_w, yb);
    gemm_bt_kernel<0><<<dim3(16, 16, 2), 256, 0, stream>>>(yb, woT, gpart, 2048, 2048, 4096);
    add_out_kernel<<<4096, 256, 0, stream>>>(gpart, out, 2048 * 2048 / 4);
}